// Round 6
// baseline (1149.142 us; speedup 1.0000x reference)
//
#include <hip/hip_runtime.h>
#include <math.h>

// Model: PINNDamageLocator
// conv1: (288,4,32,2048) -> bn+relu -> pool -> (288,16,16,512), SE1
// conv2: -> bn+relu -> pool -> (288,32,8,128), SE2
// conv3: -> bn+relu -> mean -> (288,64)
// then edge_fc + GNN + attention heads -> (reg[8,3], cls[8,9], ea[8,36])
//
// Dataflow: each thread owns ONE pooled output column and a SLICE (8 or 16)
// of output channels. The ci loop is software-pipelined with a 2-strip
// ping-pong (load next ci's rows while computing current) so HBM latency
// hides under the ~576-cycle FMA block of each iteration. Weights are read
// from LDS as float4 (ds_read_b128) to cut LDS instruction count 4x.
// R3 post-mortem: __launch_bounds__(256,4) forced VGPR=64 -> scratch spill
//   (4.5 GB HBM writes). Never use the min-waves clamp here.
// R4 post-mortem: full unroll of the ci loop kept ALL strips live -> >128
//   regs -> spill (1.5 GB scratch). Ping-pong keeps exactly 2 strips live;
//   outer loop stays `#pragma unroll 1`.
// Spill tripwire: WRITE_SIZE must stay ~166 MB for conv1; VGPR <= ~110.

// ---------------- conv1 + bn1 + relu + maxpool + SE1-sum ----------------
__global__ __launch_bounds__(512) void k_conv1(
    const float* __restrict__ x, const float* __restrict__ w,
    const float* __restrict__ cb, const float* __restrict__ bs,
    const float* __restrict__ bb, const float* __restrict__ bm,
    const float* __restrict__ bv,
    float* __restrict__ h1, float* __restrict__ sesum)
{
  int bid = blockIdx.x;                  // n*32 + ph*2 + half
  int n = bid >> 5, rem = bid & 31, ph = rem >> 1, half = rem & 1;
  int cog = threadIdx.x >> 8;            // 0,1 -> co slice cog*8..cog*8+7
  int pw = (half << 8) + (threadIdx.x & 255);   // pooled col 0..511
  __shared__ float wl[4][3][3][16];      // [ci][kh][kw][co], bn-scale folded
  __shared__ float bi[16];
  for (int i = threadIdx.x; i < 576; i += 512) {
    int co = i / 36, r = i % 36, ci = r / 9, kk = r % 9;
    float s = bs[co] * rsqrtf(bv[co] + 1e-5f);
    wl[ci][kk / 3][kk % 3][co] = w[i] * s;
  }
  if (threadIdx.x < 16) {
    int c = threadIdx.x;
    float s = bs[c] * rsqrtf(bv[c] + 1e-5f);
    bi[c] = bb[c] + (cb[c] - bm[c]) * s;
  }
  __syncthreads();
  const float* xn = x + (size_t)n * 4 * 32 * 2048;
  const bool r0ok = (ph > 0), r3ok = (ph < 15);
  const int col4 = 4 * pw;
  const int cob = cog * 8;

  float acc[2][2][8];
#pragma unroll
  for (int cr = 0; cr < 2; cr++)
#pragma unroll
    for (int cc = 0; cc < 2; cc++)
#pragma unroll
      for (int co = 0; co < 8; co++) acc[cr][cc][co] = 0.f;

  float sA[4][5], sB[4][5];
  auto load_strip = [&](int ci, float (&st)[4][5]) {
    const float* base = xn + (ci * 32 + 2 * ph - 1) * 2048;
#pragma unroll
    for (int r = 0; r < 4; r++) {
      bool ok = (r == 0) ? r0ok : ((r == 3) ? r3ok : true);
      const float* xr = base + r * 2048;
      if (ok) {
        float4 v4 = *reinterpret_cast<const float4*>(xr + col4);
        st[r][0] = pw ? xr[col4 - 1] : 0.f;
        st[r][1] = v4.x; st[r][2] = v4.y; st[r][3] = v4.z; st[r][4] = v4.w;
      } else {
        st[r][0] = st[r][1] = st[r][2] = st[r][3] = st[r][4] = 0.f;
      }
    }
  };
  auto compute = [&](int ci, const float (&st)[4][5]) {
#pragma unroll
    for (int kh = 0; kh < 3; kh++) {
#pragma unroll
      for (int kw = 0; kw < 3; kw++) {
        const float4* wv = reinterpret_cast<const float4*>(&wl[ci][kh][kw][cob]);
        float4 w0 = wv[0], w1 = wv[1];
        float wr[8] = {w0.x, w0.y, w0.z, w0.w, w1.x, w1.y, w1.z, w1.w};
#pragma unroll
        for (int cr = 0; cr < 2; cr++) {
          float v0 = st[cr + kh][kw], v1 = st[cr + kh][2 + kw];
#pragma unroll
          for (int co = 0; co < 8; co++) {
            acc[cr][0][co] = fmaf(v0, wr[co], acc[cr][0][co]);
            acc[cr][1][co] = fmaf(v1, wr[co], acc[cr][1][co]);
          }
        }
      }
    }
  };

  load_strip(0, sA);
#pragma unroll 1
  for (int ci = 0; ci < 4; ci += 2) {
    load_strip(ci + 1, sB);
    compute(ci, sA);
    load_strip(ci + 2 < 4 ? ci + 2 : 3, sA);
    compute(ci + 1, sB);
  }

  float pooled[8];
#pragma unroll
  for (int co = 0; co < 8; co++) {
    float m = fmaxf(fmaxf(acc[0][0][co], acc[0][1][co]),
                    fmaxf(acc[1][0][co], acc[1][1][co]));
    pooled[co] = fmaxf(m + bi[cob + co], 0.f);
    h1[(((size_t)n * 16 + cob + co) * 16 + ph) * 512 + pw] = pooled[co];
  }
  int lane = threadIdx.x & 63;
#pragma unroll
  for (int co = 0; co < 8; co++) {
    float v = pooled[co];
    for (int off = 32; off; off >>= 1) v += __shfl_down(v, off);
    if (lane == 0) atomicAdd(&sesum[n * 16 + cob + co], v);
  }
}

// ---------------- SE MLP (generic): mean -> relu fc -> sigmoid fc ----------------
__global__ void k_se(const float* __restrict__ sesum, int C, int Cr, float invcnt,
                     const float* __restrict__ w1, const float* __restrict__ b1,
                     const float* __restrict__ w2, const float* __restrict__ b2,
                     float* __restrict__ s)
{
  int n = blockIdx.x * blockDim.x + threadIdx.x;
  if (n >= 288) return;
  float y[32], t[8];
  for (int c = 0; c < C; c++) y[c] = sesum[n * C + c] * invcnt;
  for (int r = 0; r < Cr; r++) {
    float a = b1[r];
    for (int c = 0; c < C; c++) a += y[c] * w1[r * C + c];
    t[r] = fmaxf(a, 0.f);
  }
  for (int c = 0; c < C; c++) {
    float a = b2[c];
    for (int r = 0; r < Cr; r++) a += t[r] * w2[c * Cr + r];
    s[n * C + c] = 1.f / (1.f + expf(-a));
  }
}

// ---------------- conv2 (SE1 folded) + bn2 + relu + pool + SE2-sum ----------------
__global__ __launch_bounds__(512) void k_conv2(
    const float* __restrict__ h1, const float* __restrict__ w,
    const float* __restrict__ cb, const float* __restrict__ bs,
    const float* __restrict__ bb, const float* __restrict__ bm,
    const float* __restrict__ bv,
    const float* __restrict__ s1,
    float* __restrict__ h2, float* __restrict__ sesum)
{
  int bid = blockIdx.x;                 // n*8 + ph
  int n = bid >> 3, ph = bid & 7;
  int cog = threadIdx.x >> 7;           // 0..3 -> co slice cog*8..cog*8+7
  int wp = threadIdx.x & 127;           // pooled col 0..127
  __shared__ float wl[16][3][3][32];    // bn scale * se1 scale folded
  __shared__ float bi[32];
  const float* s1n = s1 + n * 16;
  for (int i = threadIdx.x; i < 4608; i += 512) {
    int co = i / 144, r = i % 144, ci = r / 9, kk = r % 9;
    float s = bs[co] * rsqrtf(bv[co] + 1e-5f);
    wl[ci][kk / 3][kk % 3][co] = w[i] * s * s1n[ci];
  }
  if (threadIdx.x < 32) {
    int c = threadIdx.x;
    float s = bs[c] * rsqrtf(bv[c] + 1e-5f);
    bi[c] = bb[c] + (cb[c] - bm[c]) * s;
  }
  __syncthreads();
  const float* hn = h1 + (size_t)n * 16 * 16 * 512;
  const bool r0ok = (ph > 0), r3ok = (ph < 7);
  const int col4 = 4 * wp;
  const int cob = cog * 8;

  float acc[2][2][8];
#pragma unroll
  for (int cr = 0; cr < 2; cr++)
#pragma unroll
    for (int cc = 0; cc < 2; cc++)
#pragma unroll
      for (int co = 0; co < 8; co++) acc[cr][cc][co] = 0.f;

  float sA[4][5], sB[4][5];
  auto load_strip = [&](int ci, float (&st)[4][5]) {
    const float* base = hn + (ci * 16 + 2 * ph - 1) * 512;
#pragma unroll
    for (int r = 0; r < 4; r++) {
      bool ok = (r == 0) ? r0ok : ((r == 3) ? r3ok : true);
      const float* hr = base + r * 512;
      if (ok) {
        float4 v4 = *reinterpret_cast<const float4*>(hr + col4);
        st[r][0] = wp ? hr[col4 - 1] : 0.f;
        st[r][1] = v4.x; st[r][2] = v4.y; st[r][3] = v4.z; st[r][4] = v4.w;
      } else {
        st[r][0] = st[r][1] = st[r][2] = st[r][3] = st[r][4] = 0.f;
      }
    }
  };
  auto compute = [&](int ci, const float (&st)[4][5]) {
#pragma unroll
    for (int kh = 0; kh < 3; kh++) {
#pragma unroll
      for (int kw = 0; kw < 3; kw++) {
        const float4* wv = reinterpret_cast<const float4*>(&wl[ci][kh][kw][cob]);
        float4 w0 = wv[0], w1 = wv[1];
        float wr[8] = {w0.x, w0.y, w0.z, w0.w, w1.x, w1.y, w1.z, w1.w};
#pragma unroll
        for (int cr = 0; cr < 2; cr++) {
          float v0 = st[cr + kh][kw], v1 = st[cr + kh][2 + kw];
#pragma unroll
          for (int co = 0; co < 8; co++) {
            acc[cr][0][co] = fmaf(v0, wr[co], acc[cr][0][co]);
            acc[cr][1][co] = fmaf(v1, wr[co], acc[cr][1][co]);
          }
        }
      }
    }
  };

  load_strip(0, sA);
#pragma unroll 1
  for (int ci = 0; ci < 16; ci += 2) {
    load_strip(ci + 1, sB);
    compute(ci, sA);
    load_strip(ci + 2 < 16 ? ci + 2 : 15, sA);
    compute(ci + 1, sB);
  }

  float pooled[8];
#pragma unroll
  for (int co = 0; co < 8; co++) {
    float m = fmaxf(fmaxf(acc[0][0][co], acc[0][1][co]),
                    fmaxf(acc[1][0][co], acc[1][1][co]));
    pooled[co] = fmaxf(m + bi[cob + co], 0.f);
    h2[(((size_t)n * 32 + cob + co) * 8 + ph) * 128 + wp] = pooled[co];
  }
  int lane = threadIdx.x & 63;
#pragma unroll
  for (int co = 0; co < 8; co++) {
    float v = pooled[co];
    for (int off = 32; off; off >>= 1) v += __shfl_down(v, off);
    if (lane == 0) atomicAdd(&sesum[n * 32 + cob + co], v);
  }
}

// ---------------- conv3 (SE2 folded) + bn3 + relu + global mean ----------------
__global__ __launch_bounds__(256) void k_conv3(
    const float* __restrict__ h2, const float* __restrict__ w,
    const float* __restrict__ cb, const float* __restrict__ bs,
    const float* __restrict__ bb, const float* __restrict__ bm,
    const float* __restrict__ bv,
    const float* __restrict__ s2, float* __restrict__ h3)
{
  int bid = blockIdx.x;                 // n*4 + cog (16 out channels per cog)
  int n = bid >> 2, cog = bid & 3;
  int hh = threadIdx.x >> 5;            // conv row 0..7
  int t = threadIdx.x & 31;             // conv col pair: cols 2t, 2t+1
  __shared__ float wl[32][3][3][16];    // [ci][kh][kw][k], 18 KB, scales folded
  __shared__ float bi[16];
  __shared__ float red[4][16];
  const float* s2n = s2 + n * 32;
  for (int i = threadIdx.x; i < 4608; i += 256) {
    int k = i / 288, r = i % 288, ci = r / 9, kk = r % 9;
    int co = cog * 16 + k;
    float s = bs[co] * rsqrtf(bv[co] + 1e-5f);
    wl[ci][kk / 3][kk % 3][k] = w[(size_t)co * 288 + r] * s * s2n[ci];
  }
  if (threadIdx.x < 16) {
    int c = cog * 16 + threadIdx.x;
    float s = bs[c] * rsqrtf(bv[c] + 1e-5f);
    bi[threadIdx.x] = bb[c] + (cb[c] - bm[c]) * s;
  }
  __syncthreads();
  const float* hn = h2 + (size_t)n * 32 * 8 * 128;
  const bool r0ok = (hh > 0), r2ok = (hh < 7);
  const int col4 = 4 * t;

  float acc[2][16];
#pragma unroll
  for (int cc = 0; cc < 2; cc++)
#pragma unroll
    for (int k = 0; k < 16; k++) acc[cc][k] = 0.f;

  float sA[3][5], sB[3][5];
  auto load_strip = [&](int ci, float (&st)[3][5]) {
    const float* base = hn + (ci * 8 + hh - 1) * 128;
#pragma unroll
    for (int r = 0; r < 3; r++) {
      bool ok = (r == 0) ? r0ok : ((r == 2) ? r2ok : true);
      const float* hr = base + r * 128;
      if (ok) {
        float4 v4 = *reinterpret_cast<const float4*>(hr + col4);
        st[r][0] = t ? hr[col4 - 1] : 0.f;
        st[r][1] = v4.x; st[r][2] = v4.y; st[r][3] = v4.z; st[r][4] = v4.w;
      } else {
        st[r][0] = st[r][1] = st[r][2] = st[r][3] = st[r][4] = 0.f;
      }
    }
  };
  auto compute = [&](int ci, const float (&st)[3][5]) {
#pragma unroll
    for (int kh = 0; kh < 3; kh++) {
#pragma unroll
      for (int kw = 0; kw < 3; kw++) {
        const float4* wv = reinterpret_cast<const float4*>(&wl[ci][kh][kw][0]);
        float4 w0 = wv[0], w1 = wv[1], w2 = wv[2], w3 = wv[3];
        float wr[16] = {w0.x, w0.y, w0.z, w0.w, w1.x, w1.y, w1.z, w1.w,
                        w2.x, w2.y, w2.z, w2.w, w3.x, w3.y, w3.z, w3.w};
        float v0 = st[kh][kw], v1 = st[kh][2 + kw];
#pragma unroll
        for (int k = 0; k < 16; k++) {
          acc[0][k] = fmaf(v0, wr[k], acc[0][k]);
          acc[1][k] = fmaf(v1, wr[k], acc[1][k]);
        }
      }
    }
  };

  load_strip(0, sA);
#pragma unroll 1
  for (int ci = 0; ci < 32; ci += 2) {
    load_strip(ci + 1, sB);
    compute(ci, sA);
    load_strip(ci + 2 < 32 ? ci + 2 : 31, sA);
    compute(ci + 1, sB);
  }

#pragma unroll
  for (int k = 0; k < 16; k++)
    acc[0][k] = fmaxf(acc[0][k] + bi[k], 0.f) + fmaxf(acc[1][k] + bi[k], 0.f);
  int lane = threadIdx.x & 63, wv = threadIdx.x >> 6;
#pragma unroll
  for (int k = 0; k < 16; k++) {
    float v = acc[0][k];
    for (int off = 32; off; off >>= 1) v += __shfl_down(v, off);
    if (lane == 0) red[wv][k] = v;
  }
  __syncthreads();
  if (threadIdx.x < 16) {
    int k = threadIdx.x;
    float tt = red[0][k] + red[1][k] + red[2][k] + red[3][k];
    h3[n * 64 + cog * 16 + k] = tt * (1.f / 512.f);
  }
}

// ---------------- head: edge_fc + GNN scatter + e2n + attention + outputs ----------------
__global__ __launch_bounds__(256) void k_head(
    const float* __restrict__ h3,
    const float* __restrict__ efw, const float* __restrict__ efb,
    const float* __restrict__ ew,
    const float* __restrict__ e2nw, const float* __restrict__ e2nb,
    const float* __restrict__ a1w, const float* __restrict__ a1b,
    const float* __restrict__ a2w,
    const float* __restrict__ clsw, const float* __restrict__ clsb,
    const float* __restrict__ regw, const float* __restrict__ regb,
    float* __restrict__ out)
{
  int b = blockIdx.x;
  int tid = threadIdx.x;
  __shared__ float ef[36][64];      // weighted edge features
  __shared__ float nin[12][64];
  __shared__ float nd[12][128];
  __shared__ float tmp[12][64];
  __shared__ float spw[36], aw[12], scv[12], g[128], ea[36];
  if (tid < 36) {
    float xw = ew[tid];
    spw[tid] = (xw > 20.f) ? xw : log1pf(expf(xw));   // softplus
  }
  __syncthreads();
  for (int idx = tid; idx < 36 * 64; idx += 256) {
    int e = idx >> 6, d = idx & 63;
    const float* hr = h3 + (size_t)(b * 36 + e) * 64;
    const float* wr = efw + d * 64;
    float a = efb[d];
    for (int k = 0; k < 64; k++) a += hr[k] * wr[k];
    ef[e][d] = fmaxf(a, 0.f) * spw[e];
  }
  __syncthreads();
  for (int idx = tid; idx < 12 * 64; idx += 256) {
    int j = idx >> 6, d = idx & 63;
    float a = 0.f;
    if (j < 6) { for (int i = 0; i < 6; i++) a += ef[j * 6 + i][d]; }
    else       { for (int i = 0; i < 6; i++) a += ef[i * 6 + (j - 6)][d]; }
    nin[j][d] = a;
  }
  __syncthreads();
  for (int idx = tid; idx < 12 * 128; idx += 256) {
    int j = idx >> 7, d = idx & 127;
    const float* wr = e2nw + d * 64;
    float a = e2nb[d];
    for (int k = 0; k < 64; k++) a += nin[j][k] * wr[k];
    nd[j][d] = fmaxf(a, 0.f);
  }
  __syncthreads();
  for (int idx = tid; idx < 12 * 64; idx += 256) {
    int j = idx >> 6, hh = idx & 63;
    const float* wr = a1w + hh * 128;
    float a = a1b[hh];
    for (int k = 0; k < 128; k++) a += nd[j][k] * wr[k];
    tmp[j][hh] = tanhf(a) * a2w[hh];
  }
  __syncthreads();
  if (tid < 12) {
    float a = 0.f;
    for (int h = 0; h < 64; h++) a += tmp[tid][h];
    scv[tid] = a;
  }
  __syncthreads();
  if (tid == 0) {
    float m = scv[0];
    for (int j = 1; j < 12; j++) m = fmaxf(m, scv[j]);
    float s = 0.f;
    for (int j = 0; j < 12; j++) { float z = expf(scv[j] - m); aw[j] = z; s += z; }
    float inv = 1.f / s;
    for (int j = 0; j < 12; j++) aw[j] *= inv;
    float rs = 0.f;
    for (int e = 0; e < 36; e++) { float r = aw[e / 6] * aw[6 + e % 6]; ea[e] = r; rs += r; }
    float inv2 = 1.f / (rs + 1e-8f);
    for (int e = 0; e < 36; e++) ea[e] *= inv2;
  }
  __syncthreads();
  if (tid < 36) out[96 + b * 36 + tid] = ea[tid];
  if (tid < 128) {
    float a = 0.f;
    for (int j = 0; j < 12; j++) a += nd[j][tid] * aw[j];
    g[tid] = a;
  }
  __syncthreads();
  if (tid < 3) {
    const float* wr = regw + tid * 128;
    float a = regb[tid];
    for (int k = 0; k < 128; k++) a += g[k] * wr[k];
    out[b * 3 + tid] = a;
  }
  if (tid >= 64 && tid < 73) {
    int i = tid - 64;
    const float* wr = clsw + i * 128;
    float a = clsb[i];
    for (int k = 0; k < 128; k++) a += g[k] * wr[k];
    out[24 + b * 9 + i] = a;
  }
}

extern "C" void kernel_launch(void* const* d_in, const int* in_sizes, int n_in,
                              void* d_out, int out_size, void* d_ws, size_t ws_size,
                              hipStream_t stream) {
  const float* x      = (const float*)d_in[0];
  const float* c1w    = (const float*)d_in[1];
  const float* c1b    = (const float*)d_in[2];
  const float* bn1s   = (const float*)d_in[3];
  const float* bn1b   = (const float*)d_in[4];
  const float* bn1m   = (const float*)d_in[5];
  const float* bn1v   = (const float*)d_in[6];
  const float* se1w1  = (const float*)d_in[7];
  const float* se1b1  = (const float*)d_in[8];
  const float* se1w2  = (const float*)d_in[9];
  const float* se1b2  = (const float*)d_in[10];
  const float* c2w    = (const float*)d_in[11];
  const float* c2b    = (const float*)d_in[12];
  const float* bn2s   = (const float*)d_in[13];
  const float* bn2b   = (const float*)d_in[14];
  const float* bn2m   = (const float*)d_in[15];
  const float* bn2v   = (const float*)d_in[16];
  const float* se2w1  = (const float*)d_in[17];
  const float* se2b1  = (const float*)d_in[18];
  const float* se2w2  = (const float*)d_in[19];
  const float* se2b2  = (const float*)d_in[20];
  const float* c3w    = (const float*)d_in[21];
  const float* c3b    = (const float*)d_in[22];
  const float* bn3s   = (const float*)d_in[23];
  const float* bn3b   = (const float*)d_in[24];
  const float* bn3m   = (const float*)d_in[25];
  const float* bn3v   = (const float*)d_in[26];
  const float* efw    = (const float*)d_in[27];
  const float* efb    = (const float*)d_in[28];
  const float* ew     = (const float*)d_in[29];
  const float* e2nw   = (const float*)d_in[30];
  const float* e2nb   = (const float*)d_in[31];
  const float* a1w    = (const float*)d_in[32];
  const float* a1b    = (const float*)d_in[33];
  const float* a2w    = (const float*)d_in[34];
  const float* clsw   = (const float*)d_in[35];
  const float* clsb   = (const float*)d_in[36];
  const float* regw   = (const float*)d_in[37];
  const float* regb   = (const float*)d_in[38];

  float* ws = (float*)d_ws;
  float* h1     = ws;                        // 288*16*16*512 = 37,748,736 f
  float* h2     = h1 + 37748736;             // 288*32*8*128  =  9,437,184 f
  float* sesum1 = h2 + 9437184;              // 4608 f
  float* s1     = sesum1 + 4608;             // 4608 f
  float* sesum2 = s1 + 4608;                 // 9216 f
  float* s2     = sesum2 + 9216;             // 9216 f
  float* h3     = s2 + 9216;                 // 18432 f

  hipMemsetAsync(sesum1, 0, 4608 * sizeof(float), stream);
  hipMemsetAsync(sesum2, 0, 9216 * sizeof(float), stream);

  k_conv1<<<288 * 32, 512, 0, stream>>>(x, c1w, c1b, bn1s, bn1b, bn1m, bn1v, h1, sesum1);
  k_se<<<5, 64, 0, stream>>>(sesum1, 16, 4, 1.f / 8192.f, se1w1, se1b1, se1w2, se1b2, s1);
  k_conv2<<<288 * 8, 512, 0, stream>>>(h1, c2w, c2b, bn2s, bn2b, bn2m, bn2v, s1, h2, sesum2);
  k_se<<<5, 64, 0, stream>>>(sesum2, 32, 8, 1.f / 1024.f, se2w1, se2b1, se2w2, se2b2, s2);
  k_conv3<<<288 * 4, 256, 0, stream>>>(h2, c3w, c3b, bn3s, bn3b, bn3m, bn3v, s2, h3);
  k_head<<<8, 256, 0, stream>>>(h3, efw, efb, ew, e2nw, e2nb, a1w, a1b, a2w,
                                clsw, clsb, regw, regb, (float*)d_out);
}

// Round 7
// 1042.599 us; speedup vs baseline: 1.1022x; 1.1022x over previous
//
#include <hip/hip_runtime.h>
#include <math.h>

// Model: PINNDamageLocator
// conv1: (288,4,32,2048) -> bn+relu -> pool -> (288,16,16,512), SE1
// conv2: -> bn+relu -> pool -> (288,32,8,128), SE2
// conv3: -> bn+relu -> mean -> (288,64)
// then edge_fc + GNN + attention heads -> (reg[8,3], cls[8,9], ea[8,36])
//
// conv1/conv2: canonical CDNA staging structure — each ci's 4 input rows are
// cooperatively DMA'd into LDS via __builtin_amdgcn_global_load_lds (width
// 16, linear dest = wave-uniform base + lane*16), double-buffered over ci:
//   stage(ci+1) issued BEFORE compute(ci) -> HBM latency hides under the
//   ~576-1152 FMA cycles; __syncthreads() drain is then cheap.
// Per-thread acc stays at [2][2][8]=32 regs (low VGPR, high occupancy).
// R3 post-mortem: __launch_bounds__ min-waves clamp -> forced spill. Never.
// R4 post-mortem: full ci-loop unroll -> >128 live regs -> spill. Never.
// R6 post-mortem: register ping-pong (2 strips live) -> VGPR 96, occupancy
//   20%, SLOWER than plain R5. Latency must be hidden via LDS staging +
//   cross-wave overlap, not per-thread register pipelines.
// Spill tripwire: conv1 WRITE_SIZE ~166 MB, VGPR <= ~100.

#define GLOAD_LDS(src, dst) \
  __builtin_amdgcn_global_load_lds( \
      (const __attribute__((address_space(1))) void*)(src), \
      (__attribute__((address_space(3))) void*)(dst), 16, 0, 0)

// ---------------- conv1 + bn1 + relu + maxpool + SE1-sum ----------------
// grid: n(288) x ph(16) x half(2); block 512 = cog(2) x pwl(256)
__global__ __launch_bounds__(512) void k_conv1(
    const float* __restrict__ x, const float* __restrict__ w,
    const float* __restrict__ cb, const float* __restrict__ bs,
    const float* __restrict__ bb, const float* __restrict__ bm,
    const float* __restrict__ bv,
    float* __restrict__ h1, float* __restrict__ sesum)
{
  int bid = blockIdx.x;                  // n*32 + ph*2 + half
  int n = bid >> 5, rem = bid & 31, ph = rem >> 1, half = rem & 1;
  __shared__ float body[2][4][1024];     // [buf][row][col], 32 KB
  __shared__ float wl[4][3][3][16];      // bn-scale folded
  __shared__ float bi[16];
  __shared__ float halo[4][4];           // [ci][row]: col base-1 (0 if half==0)

  const float* xn = x + (size_t)n * 4 * 32 * 2048;
  for (int i = threadIdx.x; i < 576; i += 512) {
    int co = i / 36, r = i % 36, ci = r / 9, kk = r % 9;
    float s = bs[co] * rsqrtf(bv[co] + 1e-5f);
    wl[ci][kk / 3][kk % 3][co] = w[i] * s;
  }
  if (threadIdx.x < 16) {
    int c = threadIdx.x;
    float s = bs[c] * rsqrtf(bv[c] + 1e-5f);
    bi[c] = bb[c] + (cb[c] - bm[c]) * s;
  }
  if (threadIdx.x < 16) {
    int ci = threadIdx.x >> 2, r = threadIdx.x & 3;
    int ih = min(max(2 * ph - 1 + r, 0), 31);
    halo[ci][r] = half ? xn[((size_t)ci * 32 + ih) * 2048 + 1023] : 0.f;
  }

  // staging role: wave w stages row w>>1, column-half (w&1) (512 floats = 2 DMAs)
  int wv = threadIdx.x >> 6, l = threadIdx.x & 63;
  int srow = wv >> 1, scol = (wv & 1) * 512;
  int ihc = min(max(2 * ph - 1 + srow, 0), 31);
  const float* srcrow = xn + (size_t)ihc * 2048 + half * 1024 + scol + l * 4;
  // ci stride in src: 32*2048 floats

  // prologue: stage ci=0 into buf 0
  GLOAD_LDS(srcrow, &body[0][srow][scol + l * 4]);
  GLOAD_LDS(srcrow + 256, &body[0][srow][scol + 256 + l * 4]);
  __syncthreads();

  int cog = threadIdx.x >> 8;            // 0,1
  int pwl = threadIdx.x & 255;
  int cob = cog * 8;
  const bool ok0 = (ph > 0), ok3 = (ph < 15);

  float acc[2][2][8];
#pragma unroll
  for (int cr = 0; cr < 2; cr++)
#pragma unroll
    for (int cc = 0; cc < 2; cc++)
#pragma unroll
      for (int co = 0; co < 8; co++) acc[cr][cc][co] = 0.f;

#pragma unroll 1
  for (int ci = 0; ci < 4; ci++) {
    if (ci < 3) {                        // stage next ci into other buffer
      const float* s2 = srcrow + (size_t)(ci + 1) * 32 * 2048;
      GLOAD_LDS(s2, &body[(ci + 1) & 1][srow][scol + l * 4]);
      GLOAD_LDS(s2 + 256, &body[(ci + 1) & 1][srow][scol + 256 + l * 4]);
    }
    const int b = ci & 1;
    float strip[4][5];
#pragma unroll
    for (int r = 0; r < 4; r++) {
      bool ok = (r == 0) ? ok0 : ((r == 3) ? ok3 : true);
      if (ok) {
        float4 v4 = *reinterpret_cast<const float4*>(&body[b][r][4 * pwl]);
        const float* hp = pwl ? &body[b][r][4 * pwl - 1] : &halo[ci][r];
        strip[r][0] = *hp;
        strip[r][1] = v4.x; strip[r][2] = v4.y; strip[r][3] = v4.z; strip[r][4] = v4.w;
      } else {
        strip[r][0] = strip[r][1] = strip[r][2] = strip[r][3] = strip[r][4] = 0.f;
      }
    }
#pragma unroll
    for (int kh = 0; kh < 3; kh++) {
#pragma unroll
      for (int kw = 0; kw < 3; kw++) {
        const float4* wp = reinterpret_cast<const float4*>(&wl[ci][kh][kw][cob]);
        float4 w0 = wp[0], w1 = wp[1];
        float wr[8] = {w0.x, w0.y, w0.z, w0.w, w1.x, w1.y, w1.z, w1.w};
#pragma unroll
        for (int cr = 0; cr < 2; cr++) {
          float v0 = strip[cr + kh][kw], v1 = strip[cr + kh][2 + kw];
#pragma unroll
          for (int co = 0; co < 8; co++) {
            acc[cr][0][co] = fmaf(v0, wr[co], acc[cr][0][co]);
            acc[cr][1][co] = fmaf(v1, wr[co], acc[cr][1][co]);
          }
        }
      }
    }
    if (ci < 3) __syncthreads();         // next buffer ready for everyone
  }

  int pw = half * 256 + pwl;
  float pooled[8];
#pragma unroll
  for (int co = 0; co < 8; co++) {
    float m = fmaxf(fmaxf(acc[0][0][co], acc[0][1][co]),
                    fmaxf(acc[1][0][co], acc[1][1][co]));
    pooled[co] = fmaxf(m + bi[cob + co], 0.f);
    h1[(((size_t)n * 16 + cob + co) * 16 + ph) * 512 + pw] = pooled[co];
  }
  int lane = threadIdx.x & 63;
#pragma unroll
  for (int co = 0; co < 8; co++) {
    float v = pooled[co];
    for (int off = 32; off; off >>= 1) v += __shfl_down(v, off);
    if (lane == 0) atomicAdd(&sesum[n * 16 + cob + co], v);
  }
}

// ---------------- SE MLP (generic): mean -> relu fc -> sigmoid fc ----------------
__global__ void k_se(const float* __restrict__ sesum, int C, int Cr, float invcnt,
                     const float* __restrict__ w1, const float* __restrict__ b1,
                     const float* __restrict__ w2, const float* __restrict__ b2,
                     float* __restrict__ s)
{
  int n = blockIdx.x * blockDim.x + threadIdx.x;
  if (n >= 288) return;
  float y[32], t[8];
  for (int c = 0; c < C; c++) y[c] = sesum[n * C + c] * invcnt;
  for (int r = 0; r < Cr; r++) {
    float a = b1[r];
    for (int c = 0; c < C; c++) a += y[c] * w1[r * C + c];
    t[r] = fmaxf(a, 0.f);
  }
  for (int c = 0; c < C; c++) {
    float a = b2[c];
    for (int r = 0; r < Cr; r++) a += t[r] * w2[c * Cr + r];
    s[n * C + c] = 1.f / (1.f + expf(-a));
  }
}

// ---------------- conv2 (SE1 folded) + bn2 + relu + pool + SE2-sum ----------------
// grid: n(288) x ph(8); block 512 = cog(4) x pwl(128); full 128-col width
__global__ __launch_bounds__(512) void k_conv2(
    const float* __restrict__ h1, const float* __restrict__ w,
    const float* __restrict__ cb, const float* __restrict__ bs,
    const float* __restrict__ bb, const float* __restrict__ bm,
    const float* __restrict__ bv,
    const float* __restrict__ s1,
    float* __restrict__ h2, float* __restrict__ sesum)
{
  int bid = blockIdx.x;                 // n*8 + ph
  int n = bid >> 3, ph = bid & 7;
  __shared__ float body[2][4][512];     // 16 KB
  __shared__ float wl[16][3][3][32];    // bn*se1 folded, 18 KB
  __shared__ float bi[32];

  const float* s1n = s1 + n * 16;
  for (int i = threadIdx.x; i < 4608; i += 512) {
    int co = i / 144, r = i % 144, ci = r / 9, kk = r % 9;
    float s = bs[co] * rsqrtf(bv[co] + 1e-5f);
    wl[ci][kk / 3][kk % 3][co] = w[i] * s * s1n[ci];
  }
  if (threadIdx.x < 32) {
    int c = threadIdx.x;
    float s = bs[c] * rsqrtf(bv[c] + 1e-5f);
    bi[c] = bb[c] + (cb[c] - bm[c]) * s;
  }

  const float* hn = h1 + (size_t)n * 16 * 16 * 512;
  int wv = threadIdx.x >> 6, l = threadIdx.x & 63;
  int srow = wv >> 1, scol = (wv & 1) * 256;
  int ihc = min(max(2 * ph - 1 + srow, 0), 15);
  const float* srcrow = hn + (size_t)ihc * 512 + scol + l * 4;
  // ci stride in src: 16*512 floats

  GLOAD_LDS(srcrow, &body[0][srow][scol + l * 4]);
  __syncthreads();

  int cog = threadIdx.x >> 7;           // 0..3
  int pwl = threadIdx.x & 127;
  int cob = cog * 8;
  const bool ok0 = (ph > 0), ok3 = (ph < 7);

  float acc[2][2][8];
#pragma unroll
  for (int cr = 0; cr < 2; cr++)
#pragma unroll
    for (int cc = 0; cc < 2; cc++)
#pragma unroll
      for (int co = 0; co < 8; co++) acc[cr][cc][co] = 0.f;

#pragma unroll 1
  for (int ci = 0; ci < 16; ci++) {
    if (ci < 15) {
      const float* s2 = srcrow + (size_t)(ci + 1) * 16 * 512;
      GLOAD_LDS(s2, &body[(ci + 1) & 1][srow][scol + l * 4]);
    }
    const int b = ci & 1;
    float strip[4][5];
#pragma unroll
    for (int r = 0; r < 4; r++) {
      bool ok = (r == 0) ? ok0 : ((r == 3) ? ok3 : true);
      if (ok) {
        float4 v4 = *reinterpret_cast<const float4*>(&body[b][r][4 * pwl]);
        float lv = body[b][r][pwl ? 4 * pwl - 1 : 0];
        strip[r][0] = pwl ? lv : 0.f;
        strip[r][1] = v4.x; strip[r][2] = v4.y; strip[r][3] = v4.z; strip[r][4] = v4.w;
      } else {
        strip[r][0] = strip[r][1] = strip[r][2] = strip[r][3] = strip[r][4] = 0.f;
      }
    }
#pragma unroll
    for (int kh = 0; kh < 3; kh++) {
#pragma unroll
      for (int kw = 0; kw < 3; kw++) {
        const float4* wp = reinterpret_cast<const float4*>(&wl[ci][kh][kw][cob]);
        float4 w0 = wp[0], w1 = wp[1];
        float wr[8] = {w0.x, w0.y, w0.z, w0.w, w1.x, w1.y, w1.z, w1.w};
#pragma unroll
        for (int cr = 0; cr < 2; cr++) {
          float v0 = strip[cr + kh][kw], v1 = strip[cr + kh][2 + kw];
#pragma unroll
          for (int co = 0; co < 8; co++) {
            acc[cr][0][co] = fmaf(v0, wr[co], acc[cr][0][co]);
            acc[cr][1][co] = fmaf(v1, wr[co], acc[cr][1][co]);
          }
        }
      }
    }
    if (ci < 15) __syncthreads();
  }

  float pooled[8];
#pragma unroll
  for (int co = 0; co < 8; co++) {
    float m = fmaxf(fmaxf(acc[0][0][co], acc[0][1][co]),
                    fmaxf(acc[1][0][co], acc[1][1][co]));
    pooled[co] = fmaxf(m + bi[cob + co], 0.f);
    h2[(((size_t)n * 32 + cob + co) * 8 + ph) * 128 + pwl] = pooled[co];
  }
  int lane = threadIdx.x & 63;
#pragma unroll
  for (int co = 0; co < 8; co++) {
    float v = pooled[co];
    for (int off = 32; off; off >>= 1) v += __shfl_down(v, off);
    if (lane == 0) atomicAdd(&sesum[n * 32 + cob + co], v);
  }
}

// ---------------- conv3 (SE2 folded) + bn3 + relu + global mean ----------------
__global__ __launch_bounds__(256) void k_conv3(
    const float* __restrict__ h2, const float* __restrict__ w,
    const float* __restrict__ cb, const float* __restrict__ bs,
    const float* __restrict__ bb, const float* __restrict__ bm,
    const float* __restrict__ bv,
    const float* __restrict__ s2, float* __restrict__ h3)
{
  int bid = blockIdx.x;                 // n*4 + cog (16 out channels per cog)
  int n = bid >> 2, cog = bid & 3;
  int hh = threadIdx.x >> 5;            // conv row 0..7
  int t = threadIdx.x & 31;             // conv col pair: cols 2t, 2t+1
  __shared__ float wl[32][3][3][16];    // scales folded, 18 KB
  __shared__ float bi[16];
  __shared__ float red[4][16];
  const float* s2n = s2 + n * 32;
  for (int i = threadIdx.x; i < 4608; i += 256) {
    int k = i / 288, r = i % 288, ci = r / 9, kk = r % 9;
    int co = cog * 16 + k;
    float s = bs[co] * rsqrtf(bv[co] + 1e-5f);
    wl[ci][kk / 3][kk % 3][k] = w[(size_t)co * 288 + r] * s * s2n[ci];
  }
  if (threadIdx.x < 16) {
    int c = cog * 16 + threadIdx.x;
    float s = bs[c] * rsqrtf(bv[c] + 1e-5f);
    bi[threadIdx.x] = bb[c] + (cb[c] - bm[c]) * s;
  }
  __syncthreads();
  const float* hn = h2 + (size_t)n * 32 * 8 * 128;
  const bool r0ok = (hh > 0), r2ok = (hh < 7);
  const int col4 = 4 * t;
  float acc[2][16];
#pragma unroll
  for (int cc = 0; cc < 2; cc++)
#pragma unroll
    for (int k = 0; k < 16; k++) acc[cc][k] = 0.f;
#pragma unroll 1
  for (int ci = 0; ci < 32; ci++) {
    const float* base = hn + (ci * 8 + hh - 1) * 128;
    float strip[3][5];
#pragma unroll
    for (int r = 0; r < 3; r++) {
      bool ok = (r == 0) ? r0ok : ((r == 2) ? r2ok : true);
      const float* hr = base + r * 128;
      if (ok) {
        float4 v4 = *reinterpret_cast<const float4*>(hr + col4);
        strip[r][0] = t ? hr[col4 - 1] : 0.f;
        strip[r][1] = v4.x; strip[r][2] = v4.y; strip[r][3] = v4.z; strip[r][4] = v4.w;
      } else {
        strip[r][0] = strip[r][1] = strip[r][2] = strip[r][3] = strip[r][4] = 0.f;
      }
    }
#pragma unroll
    for (int kh = 0; kh < 3; kh++) {
#pragma unroll
      for (int kw = 0; kw < 3; kw++) {
        float v0 = strip[kh][kw], v1 = strip[kh][2 + kw];
#pragma unroll
        for (int k = 0; k < 16; k++) {
          float wv = wl[ci][kh][kw][k];
          acc[0][k] = fmaf(v0, wv, acc[0][k]);
          acc[1][k] = fmaf(v1, wv, acc[1][k]);
        }
      }
    }
  }
#pragma unroll
  for (int k = 0; k < 16; k++)
    acc[0][k] = fmaxf(acc[0][k] + bi[k], 0.f) + fmaxf(acc[1][k] + bi[k], 0.f);
  int lane = threadIdx.x & 63, wvv = threadIdx.x >> 6;
#pragma unroll
  for (int k = 0; k < 16; k++) {
    float v = acc[0][k];
    for (int off = 32; off; off >>= 1) v += __shfl_down(v, off);
    if (lane == 0) red[wvv][k] = v;
  }
  __syncthreads();
  if (threadIdx.x < 16) {
    int k = threadIdx.x;
    float tt = red[0][k] + red[1][k] + red[2][k] + red[3][k];
    h3[n * 64 + cog * 16 + k] = tt * (1.f / 512.f);
  }
}

// ---------------- head: edge_fc + GNN scatter + e2n + attention + outputs ----------------
__global__ __launch_bounds__(256) void k_head(
    const float* __restrict__ h3,
    const float* __restrict__ efw, const float* __restrict__ efb,
    const float* __restrict__ ew,
    const float* __restrict__ e2nw, const float* __restrict__ e2nb,
    const float* __restrict__ a1w, const float* __restrict__ a1b,
    const float* __restrict__ a2w,
    const float* __restrict__ clsw, const float* __restrict__ clsb,
    const float* __restrict__ regw, const float* __restrict__ regb,
    float* __restrict__ out)
{
  int b = blockIdx.x;
  int tid = threadIdx.x;
  __shared__ float ef[36][64];
  __shared__ float nin[12][64];
  __shared__ float nd[12][128];
  __shared__ float tmp[12][64];
  __shared__ float spw[36], aw[12], scv[12], g[128], ea[36];
  if (tid < 36) {
    float xw = ew[tid];
    spw[tid] = (xw > 20.f) ? xw : log1pf(expf(xw));
  }
  __syncthreads();
  for (int idx = tid; idx < 36 * 64; idx += 256) {
    int e = idx >> 6, d = idx & 63;
    const float* hr = h3 + (size_t)(b * 36 + e) * 64;
    const float* wr = efw + d * 64;
    float a = efb[d];
    for (int k = 0; k < 64; k++) a += hr[k] * wr[k];
    ef[e][d] = fmaxf(a, 0.f) * spw[e];
  }
  __syncthreads();
  for (int idx = tid; idx < 12 * 64; idx += 256) {
    int j = idx >> 6, d = idx & 63;
    float a = 0.f;
    if (j < 6) { for (int i = 0; i < 6; i++) a += ef[j * 6 + i][d]; }
    else       { for (int i = 0; i < 6; i++) a += ef[i * 6 + (j - 6)][d]; }
    nin[j][d] = a;
  }
  __syncthreads();
  for (int idx = tid; idx < 12 * 128; idx += 256) {
    int j = idx >> 7, d = idx & 127;
    const float* wr = e2nw + d * 64;
    float a = e2nb[d];
    for (int k = 0; k < 64; k++) a += nin[j][k] * wr[k];
    nd[j][d] = fmaxf(a, 0.f);
  }
  __syncthreads();
  for (int idx = tid; idx < 12 * 64; idx += 256) {
    int j = idx >> 6, hh = idx & 63;
    const float* wr = a1w + hh * 128;
    float a = a1b[hh];
    for (int k = 0; k < 128; k++) a += nd[j][k] * wr[k];
    tmp[j][hh] = tanhf(a) * a2w[hh];
  }
  __syncthreads();
  if (tid < 12) {
    float a = 0.f;
    for (int h = 0; h < 64; h++) a += tmp[tid][h];
    scv[tid] = a;
  }
  __syncthreads();
  if (tid == 0) {
    float m = scv[0];
    for (int j = 1; j < 12; j++) m = fmaxf(m, scv[j]);
    float s = 0.f;
    for (int j = 0; j < 12; j++) { float z = expf(scv[j] - m); aw[j] = z; s += z; }
    float inv = 1.f / s;
    for (int j = 0; j < 12; j++) aw[j] *= inv;
    float rs = 0.f;
    for (int e = 0; e < 36; e++) { float r = aw[e / 6] * aw[6 + e % 6]; ea[e] = r; rs += r; }
    float inv2 = 1.f / (rs + 1e-8f);
    for (int e = 0; e < 36; e++) ea[e] *= inv2;
  }
  __syncthreads();
  if (tid < 36) out[96 + b * 36 + tid] = ea[tid];
  if (tid < 128) {
    float a = 0.f;
    for (int j = 0; j < 12; j++) a += nd[j][tid] * aw[j];
    g[tid] = a;
  }
  __syncthreads();
  if (tid < 3) {
    const float* wr = regw + tid * 128;
    float a = regb[tid];
    for (int k = 0; k < 128; k++) a += g[k] * wr[k];
    out[b * 3 + tid] = a;
  }
  if (tid >= 64 && tid < 73) {
    int i = tid - 64;
    const float* wr = clsw + i * 128;
    float a = clsb[i];
    for (int k = 0; k < 128; k++) a += g[k] * wr[k];
    out[24 + b * 9 + i] = a;
  }
}

extern "C" void kernel_launch(void* const* d_in, const int* in_sizes, int n_in,
                              void* d_out, int out_size, void* d_ws, size_t ws_size,
                              hipStream_t stream) {
  const float* x      = (const float*)d_in[0];
  const float* c1w    = (const float*)d_in[1];
  const float* c1b    = (const float*)d_in[2];
  const float* bn1s   = (const float*)d_in[3];
  const float* bn1b   = (const float*)d_in[4];
  const float* bn1m   = (const float*)d_in[5];
  const float* bn1v   = (const float*)d_in[6];
  const float* se1w1  = (const float*)d_in[7];
  const float* se1b1  = (const float*)d_in[8];
  const float* se1w2  = (const float*)d_in[9];
  const float* se1b2  = (const float*)d_in[10];
  const float* c2w    = (const float*)d_in[11];
  const float* c2b    = (const float*)d_in[12];
  const float* bn2s   = (const float*)d_in[13];
  const float* bn2b   = (const float*)d_in[14];
  const float* bn2m   = (const float*)d_in[15];
  const float* bn2v   = (const float*)d_in[16];
  const float* se2w1  = (const float*)d_in[17];
  const float* se2b1  = (const float*)d_in[18];
  const float* se2w2  = (const float*)d_in[19];
  const float* se2b2  = (const float*)d_in[20];
  const float* c3w    = (const float*)d_in[21];
  const float* c3b    = (const float*)d_in[22];
  const float* bn3s   = (const float*)d_in[23];
  const float* bn3b   = (const float*)d_in[24];
  const float* bn3m   = (const float*)d_in[25];
  const float* bn3v   = (const float*)d_in[26];
  const float* efw    = (const float*)d_in[27];
  const float* efb    = (const float*)d_in[28];
  const float* ew     = (const float*)d_in[29];
  const float* e2nw   = (const float*)d_in[30];
  const float* e2nb   = (const float*)d_in[31];
  const float* a1w    = (const float*)d_in[32];
  const float* a1b    = (const float*)d_in[33];
  const float* a2w    = (const float*)d_in[34];
  const float* clsw   = (const float*)d_in[35];
  const float* clsb   = (const float*)d_in[36];
  const float* regw   = (const float*)d_in[37];
  const float* regb   = (const float*)d_in[38];

  float* ws = (float*)d_ws;
  float* h1     = ws;                        // 288*16*16*512 = 37,748,736 f
  float* h2     = h1 + 37748736;             // 288*32*8*128  =  9,437,184 f
  float* sesum1 = h2 + 9437184;              // 4608 f
  float* s1     = sesum1 + 4608;             // 4608 f
  float* sesum2 = s1 + 4608;                 // 9216 f
  float* s2     = sesum2 + 9216;             // 9216 f
  float* h3     = s2 + 9216;                 // 18432 f

  hipMemsetAsync(sesum1, 0, 4608 * sizeof(float), stream);
  hipMemsetAsync(sesum2, 0, 9216 * sizeof(float), stream);

  k_conv1<<<288 * 32, 512, 0, stream>>>(x, c1w, c1b, bn1s, bn1b, bn1m, bn1v, h1, sesum1);
  k_se<<<5, 64, 0, stream>>>(sesum1, 16, 4, 1.f / 8192.f, se1w1, se1b1, se1w2, se1b2, s1);
  k_conv2<<<288 * 8, 512, 0, stream>>>(h1, c2w, c2b, bn2s, bn2b, bn2m, bn2v, s1, h2, sesum2);
  k_se<<<5, 64, 0, stream>>>(sesum2, 32, 8, 1.f / 1024.f, se2w1, se2b1, se2w2, se2b2, s2);
  k_conv3<<<288 * 4, 256, 0, stream>>>(h2, c3w, c3b, bn3s, bn3b, bn3m, bn3v, s2, h3);
  k_head<<<8, 256, 0, stream>>>(h3, efw, efb, ew, e2nw, e2nb, a1w, a1b, a2w,
                                clsw, clsb, regw, regb, (float*)d_out);
}

// Round 8
// 703.056 us; speedup vs baseline: 1.6345x; 1.4830x over previous
//
#include <hip/hip_runtime.h>
#include <math.h>

// Model: PINNDamageLocator
// conv1: (288,4,32,2048) -> bn+relu -> pool -> (288,16,16,512), SE1
// conv2: -> bn+relu -> pool -> (288,32,8,128), SE2
// conv3: -> bn+relu -> mean -> (288,64)
// then edge_fc + GNN + attention heads -> (reg[8,3], cls[8,9], ea[8,36])
//
// Structure (R8): hold ALL input channels of the current row window in LDS so
// the ci loop runs with NO barriers: compute per barrier interval is
// 2304-4608 FMA cycles/wave (vs 576 in R7) -> staged-load latency and the
// barrier drain hide under compute. Stages use full-wave global_load_lds
// (width 16, dst base+lane*16 exactly as the validated R7 pattern).
// R3: __launch_bounds__ min-waves clamp -> forced spill. Never.
// R4: full ci-loop unroll -> >128 live regs -> spill. acc stays <=32 regs.
// R6: register ping-pong -> VGPR 96, occupancy collapse. Don't.
// R7: 576 FMA cycles per barrier -> 44K cycles/block wall time. Fixed here.
// Spill tripwire: conv1 WRITE_SIZE ~166 MB, VGPR <= ~80.

#define GLOAD_LDS(src, dst) \
  __builtin_amdgcn_global_load_lds( \
      (const __attribute__((address_space(1))) void*)(src), \
      (__attribute__((address_space(3))) void*)(dst), 16, 0, 0)

// ---------------- conv1 + bn1 + relu + maxpool + SE1-sum ----------------
// grid: ((n*4 + chunk)*4 + colq), block 512 = cog(4: 4 co each) x tl(128)
__global__ __launch_bounds__(512) void k_conv1(
    const float* __restrict__ x, const float* __restrict__ w,
    const float* __restrict__ cb, const float* __restrict__ bs,
    const float* __restrict__ bb, const float* __restrict__ bm,
    const float* __restrict__ bv,
    float* __restrict__ h1, float* __restrict__ sesum)
{
  int bid = blockIdx.x;
  int colq = bid & 3, chunk = (bid >> 2) & 3, n = bid >> 4;
  __shared__ float tile[4][6][512];      // [ci][rowslot][col], 49.2 KB
  __shared__ float wl[4][3][3][16];      // bn-scale folded
  __shared__ float bi[16];
  __shared__ float haloL[4][6];          // col cbase-1 per (ci, rowslot)

  const float* xn = x + (size_t)n * 4 * 32 * 2048;
  const int cbase = colq * 512;
  for (int i = threadIdx.x; i < 576; i += 512) {
    int co = i / 36, r = i % 36, ci = r / 9, kk = r % 9;
    float s = bs[co] * rsqrtf(bv[co] + 1e-5f);
    wl[ci][kk / 3][kk % 3][co] = w[i] * s;
  }
  if (threadIdx.x < 16) {
    int c = threadIdx.x;
    float s = bs[c] * rsqrtf(bv[c] + 1e-5f);
    bi[c] = bb[c] + (cb[c] - bm[c]) * s;
  }
  int wv = threadIdx.x >> 6, l = threadIdx.x & 63;
  const int P0 = chunk * 4;
  {  // prologue: stage input rows 2P0-1 .. 2P0+2 for all 4 ci
    int rowidx = wv & 3;
    int ih = 2 * P0 - 1 + rowidx;
    int slot = ((ih % 6) + 6) % 6;
    int ihc = min(max(ih, 0), 31);
#pragma unroll
    for (int h = 0; h < 2; h++) {
      int ci = (wv >> 2) + 2 * h;
      const float* src = xn + ((size_t)ci * 32 + ihc) * 2048 + cbase + 4 * l;
      GLOAD_LDS(src, &tile[ci][slot][4 * l]);
      GLOAD_LDS(src + 256, &tile[ci][slot][256 + 4 * l]);
    }
    if (threadIdx.x < 16) {
      int ri = threadIdx.x & 3, ci = threadIdx.x >> 2;
      int ih2 = 2 * P0 - 1 + ri, slot2 = ((ih2 % 6) + 6) % 6;
      int ihc2 = min(max(ih2, 0), 31);
      haloL[ci][slot2] = colq ? xn[((size_t)ci * 32 + ihc2) * 2048 + cbase - 1] : 0.f;
    }
  }
  __syncthreads();

  int cog = threadIdx.x >> 7, tl = threadIdx.x & 127;
  int cob = cog * 4;
  float sloc[4] = {0.f, 0.f, 0.f, 0.f};

#pragma unroll 1
  for (int pl = 0; pl < 4; pl++) {
    int p = P0 + pl;
    if (pl < 3) {  // stage rows 2p+3, 2p+4 (for prow p+1)
      int rsel = wv & 1, ci = wv >> 1;
      int ih = 2 * p + 3 + rsel;
      int slot = ih % 6;
      int ihc = min(ih, 31);
      const float* src = xn + ((size_t)ci * 32 + ihc) * 2048 + cbase + 4 * l;
      GLOAD_LDS(src, &tile[ci][slot][4 * l]);
      GLOAD_LDS(src + 256, &tile[ci][slot][256 + 4 * l]);
      if (threadIdx.x < 8) {
        int rs2 = threadIdx.x & 1, ci2 = threadIdx.x >> 1;
        int ih2 = 2 * p + 3 + rs2, slot2 = ih2 % 6, ihc2 = min(ih2, 31);
        haloL[ci2][slot2] = colq ? xn[((size_t)ci2 * 32 + ihc2) * 2048 + cbase - 1] : 0.f;
      }
    }
    // compute prow p: all 4 ci from LDS, no barriers
    float acc[2][2][4];
#pragma unroll
    for (int cr = 0; cr < 2; cr++)
#pragma unroll
      for (int cc = 0; cc < 2; cc++)
#pragma unroll
        for (int k = 0; k < 4; k++) acc[cr][cc][k] = 0.f;
    const bool ok0 = (p > 0), ok3 = (p < 15);
    int slots[4];
#pragma unroll
    for (int r = 0; r < 4; r++) {
      int ih = 2 * p - 1 + r;
      slots[r] = ((ih % 6) + 6) % 6;
    }
#pragma unroll 1
    for (int ci = 0; ci < 4; ci++) {
      float strip[4][5];
#pragma unroll
      for (int r = 0; r < 4; r++) {
        bool ok = (r == 0) ? ok0 : ((r == 3) ? ok3 : true);
        if (ok) {
          float4 v4 = *reinterpret_cast<const float4*>(&tile[ci][slots[r]][4 * tl]);
          float lv = __shfl_up(v4.w, 1);
          if (l == 0) lv = tl ? tile[ci][slots[r]][4 * tl - 1] : haloL[ci][slots[r]];
          strip[r][0] = lv;
          strip[r][1] = v4.x; strip[r][2] = v4.y; strip[r][3] = v4.z; strip[r][4] = v4.w;
        } else {
          strip[r][0] = strip[r][1] = strip[r][2] = strip[r][3] = strip[r][4] = 0.f;
        }
      }
#pragma unroll
      for (int kh = 0; kh < 3; kh++) {
#pragma unroll
        for (int kw = 0; kw < 3; kw++) {
          float4 wv4 = *reinterpret_cast<const float4*>(&wl[ci][kh][kw][cob]);
          float wr[4] = {wv4.x, wv4.y, wv4.z, wv4.w};
#pragma unroll
          for (int cr = 0; cr < 2; cr++) {
            float v0 = strip[cr + kh][kw], v1 = strip[cr + kh][2 + kw];
#pragma unroll
            for (int k = 0; k < 4; k++) {
              acc[cr][0][k] = fmaf(v0, wr[k], acc[cr][0][k]);
              acc[cr][1][k] = fmaf(v1, wr[k], acc[cr][1][k]);
            }
          }
        }
      }
    }
    int pc = colq * 128 + tl;
#pragma unroll
    for (int k = 0; k < 4; k++) {
      float m = fmaxf(fmaxf(acc[0][0][k], acc[0][1][k]),
                      fmaxf(acc[1][0][k], acc[1][1][k]));
      float po = fmaxf(m + bi[cob + k], 0.f);
      h1[(((size_t)n * 16 + cob + k) * 16 + p) * 512 + pc] = po;
      sloc[k] += po;
    }
    __syncthreads();
  }
#pragma unroll
  for (int k = 0; k < 4; k++) {
    float v = sloc[k];
    for (int off = 32; off; off >>= 1) v += __shfl_down(v, off);
    if (l == 0) atomicAdd(&sesum[n * 16 + cob + k], v);
  }
}

// ---------------- SE MLP (generic): mean -> relu fc -> sigmoid fc ----------------
__global__ void k_se(const float* __restrict__ sesum, int C, int Cr, float invcnt,
                     const float* __restrict__ w1, const float* __restrict__ b1,
                     const float* __restrict__ w2, const float* __restrict__ b2,
                     float* __restrict__ s)
{
  int n = blockIdx.x * blockDim.x + threadIdx.x;
  if (n >= 288) return;
  float y[32], t[8];
  for (int c = 0; c < C; c++) y[c] = sesum[n * C + c] * invcnt;
  for (int r = 0; r < Cr; r++) {
    float a = b1[r];
    for (int c = 0; c < C; c++) a += y[c] * w1[r * C + c];
    t[r] = fmaxf(a, 0.f);
  }
  for (int c = 0; c < C; c++) {
    float a = b2[c];
    for (int r = 0; r < Cr; r++) a += t[r] * w2[c * Cr + r];
    s[n * C + c] = 1.f / (1.f + expf(-a));
  }
}

// ---------------- conv2 (SE1 folded) + bn2 + relu + pool + SE2-sum ----------------
// grid: ((n*8 + ph)*2 + colh), block 512 = cog(8: 4 co each) x tl(64)
__global__ __launch_bounds__(512) void k_conv2(
    const float* __restrict__ h1, const float* __restrict__ w,
    const float* __restrict__ cb, const float* __restrict__ bs,
    const float* __restrict__ bb, const float* __restrict__ bm,
    const float* __restrict__ bv,
    const float* __restrict__ s1,
    float* __restrict__ h2, float* __restrict__ sesum)
{
  int bid = blockIdx.x;
  int colh = bid & 1, ph = (bid >> 1) & 7, n = bid >> 4;
  __shared__ float tile[2][8][4][256];   // [buf][ci][row][col], 32.8 KB
  __shared__ float wl[16][3][3][32];     // bn*se1 folded, 18.4 KB
  __shared__ float bi[32];
  __shared__ float haloL[2][8][4];

  const float* s1n = s1 + n * 16;
  for (int i = threadIdx.x; i < 4608; i += 512) {
    int co = i / 144, r = i % 144, ci = r / 9, kk = r % 9;
    float s = bs[co] * rsqrtf(bv[co] + 1e-5f);
    wl[ci][kk / 3][kk % 3][co] = w[i] * s * s1n[ci];
  }
  if (threadIdx.x < 32) {
    int c = threadIdx.x;
    float s = bs[c] * rsqrtf(bv[c] + 1e-5f);
    bi[c] = bb[c] + (cb[c] - bm[c]) * s;
  }
  const float* hn = h1 + (size_t)n * 16 * 16 * 512;
  const int cb2 = colh * 256;
  int wv = threadIdx.x >> 6, l = threadIdx.x & 63;

  // stage chunk c (ci = c*8 .. c*8+7) into buf c
#define C2_STAGE(c)                                                          \
  {                                                                          \
    for (int i = 0; i < 4; i++) {                                            \
      int pair = wv * 4 + i;                                                 \
      int ci_l = pair >> 2, r = pair & 3;                                    \
      int ci = (c) * 8 + ci_l;                                               \
      int ih = min(max(2 * ph - 1 + r, 0), 15);                              \
      const float* src = hn + ((size_t)ci * 16 + ih) * 512 + cb2 + 4 * l;    \
      GLOAD_LDS(src, &tile[c][ci_l][r][4 * l]);                              \
    }                                                                        \
    if (threadIdx.x < 32) {                                                  \
      int ci_l = threadIdx.x >> 2, r = threadIdx.x & 3;                      \
      int ci = (c) * 8 + ci_l;                                               \
      int ih = min(max(2 * ph - 1 + r, 0), 15);                              \
      haloL[c][ci_l][r] =                                                    \
          colh ? hn[((size_t)ci * 16 + ih) * 512 + cb2 - 1] : 0.f;           \
    }                                                                        \
  }

  C2_STAGE(0);
  __syncthreads();
  C2_STAGE(1);

  int cog = threadIdx.x >> 6, tl = threadIdx.x & 63;
  int cob = cog * 4;
  const bool ok0 = (ph > 0), ok3 = (ph < 7);
  float acc[2][2][4];
#pragma unroll
  for (int cr = 0; cr < 2; cr++)
#pragma unroll
    for (int cc = 0; cc < 2; cc++)
#pragma unroll
      for (int k = 0; k < 4; k++) acc[cr][cc][k] = 0.f;

#pragma unroll 1
  for (int c = 0; c < 2; c++) {
#pragma unroll 1
    for (int ci_l = 0; ci_l < 8; ci_l++) {
      int cg = c * 8 + ci_l;
      float strip[4][5];
#pragma unroll
      for (int r = 0; r < 4; r++) {
        bool ok = (r == 0) ? ok0 : ((r == 3) ? ok3 : true);
        if (ok) {
          float4 v4 = *reinterpret_cast<const float4*>(&tile[c][ci_l][r][4 * tl]);
          float lv = __shfl_up(v4.w, 1);
          if (l == 0) lv = tl ? tile[c][ci_l][r][4 * tl - 1] : haloL[c][ci_l][r];
          strip[r][0] = lv;
          strip[r][1] = v4.x; strip[r][2] = v4.y; strip[r][3] = v4.z; strip[r][4] = v4.w;
        } else {
          strip[r][0] = strip[r][1] = strip[r][2] = strip[r][3] = strip[r][4] = 0.f;
        }
      }
#pragma unroll
      for (int kh = 0; kh < 3; kh++) {
#pragma unroll
        for (int kw = 0; kw < 3; kw++) {
          float4 wv4 = *reinterpret_cast<const float4*>(&wl[cg][kh][kw][cob]);
          float wr[4] = {wv4.x, wv4.y, wv4.z, wv4.w};
#pragma unroll
          for (int cr = 0; cr < 2; cr++) {
            float v0 = strip[cr + kh][kw], v1 = strip[cr + kh][2 + kw];
#pragma unroll
            for (int k = 0; k < 4; k++) {
              acc[cr][0][k] = fmaf(v0, wr[k], acc[cr][0][k]);
              acc[cr][1][k] = fmaf(v1, wr[k], acc[cr][1][k]);
            }
          }
        }
      }
    }
    if (c == 0) __syncthreads();  // buf1 staged; its latency hid under chunk-0 compute
  }

  int pc = colh * 64 + tl;
#pragma unroll
  for (int k = 0; k < 4; k++) {
    float m = fmaxf(fmaxf(acc[0][0][k], acc[0][1][k]),
                    fmaxf(acc[1][0][k], acc[1][1][k]));
    float po = fmaxf(m + bi[cob + k], 0.f);
    h2[(((size_t)n * 32 + cob + k) * 8 + ph) * 128 + pc] = po;
    float v = po;
    for (int off = 32; off; off >>= 1) v += __shfl_down(v, off);
    if (l == 0) atomicAdd(&sesum[n * 32 + cob + k], v);
  }
}

// ---------------- conv3 (SE2 folded) + bn3 + relu + global mean ----------------
// grid: n*4 + cog16 (16 co each), block 256 = hh(8) x t(32)
__global__ __launch_bounds__(256) void k_conv3(
    const float* __restrict__ h2, const float* __restrict__ w,
    const float* __restrict__ cb, const float* __restrict__ bs,
    const float* __restrict__ bb, const float* __restrict__ bm,
    const float* __restrict__ bv,
    const float* __restrict__ s2, float* __restrict__ h3)
{
  int bid = blockIdx.x;
  int n = bid >> 2, cog = bid & 3;
  int hh = threadIdx.x >> 5, t = threadIdx.x & 31;
  __shared__ float tile[8][8][128];     // [ci_l][row][col], 32 KB
  __shared__ float wl[32][3][3][16];    // scales folded, 18.4 KB
  __shared__ float bi[16];
  __shared__ float red[4][16];
  const float* s2n = s2 + n * 32;
  for (int i = threadIdx.x; i < 4608; i += 256) {
    int k = i / 288, r = i % 288, ci = r / 9, kk = r % 9;
    int co = cog * 16 + k;
    float s = bs[co] * rsqrtf(bv[co] + 1e-5f);
    wl[ci][kk / 3][kk % 3][k] = w[(size_t)co * 288 + r] * s * s2n[ci];
  }
  if (threadIdx.x < 16) {
    int c = cog * 16 + threadIdx.x;
    float s = bs[c] * rsqrtf(bv[c] + 1e-5f);
    bi[threadIdx.x] = bb[c] + (cb[c] - bm[c]) * s;
  }
  const float* hn = h2 + (size_t)n * 32 * 8 * 128;
  int wv = threadIdx.x >> 6, l = threadIdx.x & 63;
  float acc[2][16];
#pragma unroll
  for (int cc = 0; cc < 2; cc++)
#pragma unroll
    for (int k = 0; k < 16; k++) acc[cc][k] = 0.f;

#pragma unroll 1
  for (int c = 0; c < 4; c++) {
    // stage 8 ci x 8 rows; one full-wave GLOAD covers 2 rows (256 floats)
    for (int i = 0; i < 8; i++) {
      int pair = wv * 8 + i;
      int ci_l = pair >> 2, r2 = (pair & 3) * 2;
      int ci = c * 8 + ci_l;
      const float* src = hn + ((size_t)ci * 8 + r2) * 128 + 4 * l;
      GLOAD_LDS(src, &tile[ci_l][r2][4 * l]);
    }
    __syncthreads();
#pragma unroll 1
    for (int ci_l = 0; ci_l < 8; ci_l++) {
      int cg = c * 8 + ci_l;
      float strip[3][5];
#pragma unroll
      for (int r = 0; r < 3; r++) {
        int ih = hh - 1 + r;
        if (ih >= 0 && ih <= 7) {
          float4 v4 = *reinterpret_cast<const float4*>(&tile[ci_l][ih][4 * t]);
          float lv = __shfl_up(v4.w, 1);
          if (t == 0) lv = 0.f;   // input col -1
          strip[r][0] = lv;
          strip[r][1] = v4.x; strip[r][2] = v4.y; strip[r][3] = v4.z; strip[r][4] = v4.w;
        } else {
          strip[r][0] = strip[r][1] = strip[r][2] = strip[r][3] = strip[r][4] = 0.f;
        }
      }
#pragma unroll
      for (int kh = 0; kh < 3; kh++) {
#pragma unroll
        for (int kw = 0; kw < 3; kw++) {
          const float4* wp = reinterpret_cast<const float4*>(&wl[cg][kh][kw][0]);
          float4 w0 = wp[0], w1 = wp[1], w2 = wp[2], w3 = wp[3];
          float wr[16] = {w0.x, w0.y, w0.z, w0.w, w1.x, w1.y, w1.z, w1.w,
                          w2.x, w2.y, w2.z, w2.w, w3.x, w3.y, w3.z, w3.w};
          float v0 = strip[kh][kw], v1 = strip[kh][2 + kw];
#pragma unroll
          for (int k = 0; k < 16; k++) {
            acc[0][k] = fmaf(v0, wr[k], acc[0][k]);
            acc[1][k] = fmaf(v1, wr[k], acc[1][k]);
          }
        }
      }
    }
    __syncthreads();
  }
#pragma unroll
  for (int k = 0; k < 16; k++)
    acc[0][k] = fmaxf(acc[0][k] + bi[k], 0.f) + fmaxf(acc[1][k] + bi[k], 0.f);
#pragma unroll
  for (int k = 0; k < 16; k++) {
    float v = acc[0][k];
    for (int off = 32; off; off >>= 1) v += __shfl_down(v, off);
    if (l == 0) red[wv][k] = v;
  }
  __syncthreads();
  if (threadIdx.x < 16) {
    int k = threadIdx.x;
    float tt = red[0][k] + red[1][k] + red[2][k] + red[3][k];
    h3[n * 64 + cog * 16 + k] = tt * (1.f / 512.f);
  }
}

// ---------------- head: edge_fc + GNN scatter + e2n + attention + outputs ----------------
__global__ __launch_bounds__(256) void k_head(
    const float* __restrict__ h3,
    const float* __restrict__ efw, const float* __restrict__ efb,
    const float* __restrict__ ew,
    const float* __restrict__ e2nw, const float* __restrict__ e2nb,
    const float* __restrict__ a1w, const float* __restrict__ a1b,
    const float* __restrict__ a2w,
    const float* __restrict__ clsw, const float* __restrict__ clsb,
    const float* __restrict__ regw, const float* __restrict__ regb,
    float* __restrict__ out)
{
  int b = blockIdx.x;
  int tid = threadIdx.x;
  __shared__ float ef[36][64];
  __shared__ float nin[12][64];
  __shared__ float nd[12][128];
  __shared__ float tmp[12][64];
  __shared__ float spw[36], aw[12], scv[12], g[128], ea[36];
  if (tid < 36) {
    float xw = ew[tid];
    spw[tid] = (xw > 20.f) ? xw : log1pf(expf(xw));
  }
  __syncthreads();
  for (int idx = tid; idx < 36 * 64; idx += 256) {
    int e = idx >> 6, d = idx & 63;
    const float* hr = h3 + (size_t)(b * 36 + e) * 64;
    const float* wr = efw + d * 64;
    float a = efb[d];
    for (int k = 0; k < 64; k++) a += hr[k] * wr[k];
    ef[e][d] = fmaxf(a, 0.f) * spw[e];
  }
  __syncthreads();
  for (int idx = tid; idx < 12 * 64; idx += 256) {
    int j = idx >> 6, d = idx & 63;
    float a = 0.f;
    if (j < 6) { for (int i = 0; i < 6; i++) a += ef[j * 6 + i][d]; }
    else       { for (int i = 0; i < 6; i++) a += ef[i * 6 + (j - 6)][d]; }
    nin[j][d] = a;
  }
  __syncthreads();
  for (int idx = tid; idx < 12 * 128; idx += 256) {
    int j = idx >> 7, d = idx & 127;
    const float* wr = e2nw + d * 64;
    float a = e2nb[d];
    for (int k = 0; k < 64; k++) a += nin[j][k] * wr[k];
    nd[j][d] = fmaxf(a, 0.f);
  }
  __syncthreads();
  for (int idx = tid; idx < 12 * 64; idx += 256) {
    int j = idx >> 6, hh = idx & 63;
    const float* wr = a1w + hh * 128;
    float a = a1b[hh];
    for (int k = 0; k < 128; k++) a += nd[j][k] * wr[k];
    tmp[j][hh] = tanhf(a) * a2w[hh];
  }
  __syncthreads();
  if (tid < 12) {
    float a = 0.f;
    for (int h = 0; h < 64; h++) a += tmp[tid][h];
    scv[tid] = a;
  }
  __syncthreads();
  if (tid == 0) {
    float m = scv[0];
    for (int j = 1; j < 12; j++) m = fmaxf(m, scv[j]);
    float s = 0.f;
    for (int j = 0; j < 12; j++) { float z = expf(scv[j] - m); aw[j] = z; s += z; }
    float inv = 1.f / s;
    for (int j = 0; j < 12; j++) aw[j] *= inv;
    float rs = 0.f;
    for (int e = 0; e < 36; e++) { float r = aw[e / 6] * aw[6 + e % 6]; ea[e] = r; rs += r; }
    float inv2 = 1.f / (rs + 1e-8f);
    for (int e = 0; e < 36; e++) ea[e] *= inv2;
  }
  __syncthreads();
  if (tid < 36) out[96 + b * 36 + tid] = ea[tid];
  if (tid < 128) {
    float a = 0.f;
    for (int j = 0; j < 12; j++) a += nd[j][tid] * aw[j];
    g[tid] = a;
  }
  __syncthreads();
  if (tid < 3) {
    const float* wr = regw + tid * 128;
    float a = regb[tid];
    for (int k = 0; k < 128; k++) a += g[k] * wr[k];
    out[b * 3 + tid] = a;
  }
  if (tid >= 64 && tid < 73) {
    int i = tid - 64;
    const float* wr = clsw + i * 128;
    float a = clsb[i];
    for (int k = 0; k < 128; k++) a += g[k] * wr[k];
    out[24 + b * 9 + i] = a;
  }
}

extern "C" void kernel_launch(void* const* d_in, const int* in_sizes, int n_in,
                              void* d_out, int out_size, void* d_ws, size_t ws_size,
                              hipStream_t stream) {
  const float* x      = (const float*)d_in[0];
  const float* c1w    = (const float*)d_in[1];
  const float* c1b    = (const float*)d_in[2];
  const float* bn1s   = (const float*)d_in[3];
  const float* bn1b   = (const float*)d_in[4];
  const float* bn1m   = (const float*)d_in[5];
  const float* bn1v   = (const float*)d_in[6];
  const float* se1w1  = (const float*)d_in[7];
  const float* se1b1  = (const float*)d_in[8];
  const float* se1w2  = (const float*)d_in[9];
  const float* se1b2  = (const float*)d_in[10];
  const float* c2w    = (const float*)d_in[11];
  const float* c2b    = (const float*)d_in[12];
  const float* bn2s   = (const float*)d_in[13];
  const float* bn2b   = (const float*)d_in[14];
  const float* bn2m   = (const float*)d_in[15];
  const float* bn2v   = (const float*)d_in[16];
  const float* se2w1  = (const float*)d_in[17];
  const float* se2b1  = (const float*)d_in[18];
  const float* se2w2  = (const float*)d_in[19];
  const float* se2b2  = (const float*)d_in[20];
  const float* c3w    = (const float*)d_in[21];
  const float* c3b    = (const float*)d_in[22];
  const float* bn3s   = (const float*)d_in[23];
  const float* bn3b   = (const float*)d_in[24];
  const float* bn3m   = (const float*)d_in[25];
  const float* bn3v   = (const float*)d_in[26];
  const float* efw    = (const float*)d_in[27];
  const float* efb    = (const float*)d_in[28];
  const float* ew     = (const float*)d_in[29];
  const float* e2nw   = (const float*)d_in[30];
  const float* e2nb   = (const float*)d_in[31];
  const float* a1w    = (const float*)d_in[32];
  const float* a1b    = (const float*)d_in[33];
  const float* a2w    = (const float*)d_in[34];
  const float* clsw   = (const float*)d_in[35];
  const float* clsb   = (const float*)d_in[36];
  const float* regw   = (const float*)d_in[37];
  const float* regb   = (const float*)d_in[38];

  float* ws = (float*)d_ws;
  float* h1     = ws;                        // 288*16*16*512 = 37,748,736 f
  float* h2     = h1 + 37748736;             // 288*32*8*128  =  9,437,184 f
  float* sesum1 = h2 + 9437184;              // 4608 f
  float* s1     = sesum1 + 4608;             // 4608 f
  float* sesum2 = s1 + 4608;                 // 9216 f
  float* s2     = sesum2 + 9216;             // 9216 f
  float* h3     = s2 + 9216;                 // 18432 f

  hipMemsetAsync(sesum1, 0, 4608 * sizeof(float), stream);
  hipMemsetAsync(sesum2, 0, 9216 * sizeof(float), stream);

  k_conv1<<<288 * 16, 512, 0, stream>>>(x, c1w, c1b, bn1s, bn1b, bn1m, bn1v, h1, sesum1);
  k_se<<<5, 64, 0, stream>>>(sesum1, 16, 4, 1.f / 8192.f, se1w1, se1b1, se1w2, se1b2, s1);
  k_conv2<<<288 * 16, 512, 0, stream>>>(h1, c2w, c2b, bn2s, bn2b, bn2m, bn2v, s1, h2, sesum2);
  k_se<<<5, 64, 0, stream>>>(sesum2, 32, 8, 1.f / 1024.f, se2w1, se2b1, se2w2, se2b2, s2);
  k_conv3<<<288 * 4, 256, 0, stream>>>(h2, c3w, c3b, bn3s, bn3b, bn3m, bn3v, s2, h3);
  k_head<<<8, 256, 0, stream>>>(h3, efw, efb, ew, e2nw, e2nb, a1w, a1b, a2w,
                                clsw, clsb, regw, regb, (float*)d_out);
}

// Round 9
// 573.910 us; speedup vs baseline: 2.0023x; 1.2250x over previous
//
#include <hip/hip_runtime.h>
#include <math.h>

// Model: PINNDamageLocator
// conv1: (288,4,32,2048) -> bn+relu -> pool -> (288,16,16,512), SE1
// conv2: -> bn+relu -> pool -> (288,32,8,128), SE2
// conv3: -> bn+relu -> mean -> (288,64)
// then edge_fc + GNN + attention heads -> (reg[8,3], cls[8,9], ea[8,36])
//
// R8 lesson: compute-per-barrier must be >=~1152 FMA cycles AND LDS <= ~52KB
// so 3 blocks/CU stay resident (R8 conv2 at 84.5KB -> 1 block/CU -> 300us).
// R9: conv2 rewritten full-width, 8 co/thread, 2-ci double-buffered chunks,
// 52 KB LDS. All halo handling via LDS address-select scalar reads (no
// __shfl_up / ds_bpermute, no divergent patches).
// R3: never use __launch_bounds__ min-waves clamp (forced spill).
// R4: never fully unroll ci loops (>128 live regs -> spill).
// R6: no per-thread register ping-pong (VGPR 96 -> occupancy collapse).
// Spill tripwire: WRITE_SIZE ~= ideal, VGPR <= ~90.

#define GLOAD_LDS(src, dst) \
  __builtin_amdgcn_global_load_lds( \
      (const __attribute__((address_space(1))) void*)(src), \
      (__attribute__((address_space(3))) void*)(dst), 16, 0, 0)

// ---------------- conv1 + bn1 + relu + maxpool + SE1-sum ----------------
// grid: ((n*4 + chunk)*4 + colq), block 512 = cog(4: 4 co each) x tl(128)
__global__ __launch_bounds__(512) void k_conv1(
    const float* __restrict__ x, const float* __restrict__ w,
    const float* __restrict__ cb, const float* __restrict__ bs,
    const float* __restrict__ bb, const float* __restrict__ bm,
    const float* __restrict__ bv,
    float* __restrict__ h1, float* __restrict__ sesum)
{
  int bid = blockIdx.x;
  int colq = bid & 3, chunk = (bid >> 2) & 3, n = bid >> 4;
  __shared__ float tile[4][6][512];      // [ci][rowslot][col], 49.2 KB
  __shared__ float wl[4][3][3][16];      // bn-scale folded
  __shared__ float bi[16];
  __shared__ float haloL[4][6];          // col cbase-1 per (ci, rowslot)

  const float* xn = x + (size_t)n * 4 * 32 * 2048;
  const int cbase = colq * 512;
  for (int i = threadIdx.x; i < 576; i += 512) {
    int co = i / 36, r = i % 36, ci = r / 9, kk = r % 9;
    float s = bs[co] * rsqrtf(bv[co] + 1e-5f);
    wl[ci][kk / 3][kk % 3][co] = w[i] * s;
  }
  if (threadIdx.x < 16) {
    int c = threadIdx.x;
    float s = bs[c] * rsqrtf(bv[c] + 1e-5f);
    bi[c] = bb[c] + (cb[c] - bm[c]) * s;
  }
  int wv = threadIdx.x >> 6, l = threadIdx.x & 63;
  const int P0 = chunk * 4;
  {  // prologue: stage input rows 2P0-1 .. 2P0+2 for all 4 ci
    int rowidx = wv & 3;
    int ih = 2 * P0 - 1 + rowidx;
    int slot = ((ih % 6) + 6) % 6;
    int ihc = min(max(ih, 0), 31);
#pragma unroll
    for (int h = 0; h < 2; h++) {
      int ci = (wv >> 2) + 2 * h;
      const float* src = xn + ((size_t)ci * 32 + ihc) * 2048 + cbase + 4 * l;
      GLOAD_LDS(src, &tile[ci][slot][4 * l]);
      GLOAD_LDS(src + 256, &tile[ci][slot][256 + 4 * l]);
    }
    if (threadIdx.x < 16) {
      int ri = threadIdx.x & 3, ci = threadIdx.x >> 2;
      int ih2 = 2 * P0 - 1 + ri, slot2 = ((ih2 % 6) + 6) % 6;
      int ihc2 = min(max(ih2, 0), 31);
      haloL[ci][slot2] = colq ? xn[((size_t)ci * 32 + ihc2) * 2048 + cbase - 1] : 0.f;
    }
  }
  __syncthreads();

  int cog = threadIdx.x >> 7, tl = threadIdx.x & 127;
  int cob = cog * 4;
  float sloc[4] = {0.f, 0.f, 0.f, 0.f};

#pragma unroll 1
  for (int pl = 0; pl < 4; pl++) {
    int p = P0 + pl;
    if (pl < 3) {  // stage rows 2p+3, 2p+4 (for prow p+1)
      int rsel = wv & 1, ci = wv >> 1;
      int ih = 2 * p + 3 + rsel;
      int slot = ih % 6;
      int ihc = min(ih, 31);
      const float* src = xn + ((size_t)ci * 32 + ihc) * 2048 + cbase + 4 * l;
      GLOAD_LDS(src, &tile[ci][slot][4 * l]);
      GLOAD_LDS(src + 256, &tile[ci][slot][256 + 4 * l]);
      if (threadIdx.x < 8) {
        int rs2 = threadIdx.x & 1, ci2 = threadIdx.x >> 1;
        int ih2 = 2 * p + 3 + rs2, slot2 = ih2 % 6, ihc2 = min(ih2, 31);
        haloL[ci2][slot2] = colq ? xn[((size_t)ci2 * 32 + ihc2) * 2048 + cbase - 1] : 0.f;
      }
    }
    // compute prow p: all 4 ci from LDS, no barriers
    float acc[2][2][4];
#pragma unroll
    for (int cr = 0; cr < 2; cr++)
#pragma unroll
      for (int cc = 0; cc < 2; cc++)
#pragma unroll
        for (int k = 0; k < 4; k++) acc[cr][cc][k] = 0.f;
    const bool ok0 = (p > 0), ok3 = (p < 15);
    int slots[4];
#pragma unroll
    for (int r = 0; r < 4; r++) {
      int ih = 2 * p - 1 + r;
      slots[r] = ((ih % 6) + 6) % 6;
    }
#pragma unroll 1
    for (int ci = 0; ci < 4; ci++) {
      float strip[4][5];
#pragma unroll
      for (int r = 0; r < 4; r++) {
        bool ok = (r == 0) ? ok0 : ((r == 3) ? ok3 : true);
        if (ok) {
          float4 v4 = *reinterpret_cast<const float4*>(&tile[ci][slots[r]][4 * tl]);
          const float* ap = tl ? &tile[ci][slots[r]][4 * tl - 1] : &haloL[ci][slots[r]];
          strip[r][0] = *ap;
          strip[r][1] = v4.x; strip[r][2] = v4.y; strip[r][3] = v4.z; strip[r][4] = v4.w;
        } else {
          strip[r][0] = strip[r][1] = strip[r][2] = strip[r][3] = strip[r][4] = 0.f;
        }
      }
#pragma unroll
      for (int kh = 0; kh < 3; kh++) {
#pragma unroll
        for (int kw = 0; kw < 3; kw++) {
          float4 wv4 = *reinterpret_cast<const float4*>(&wl[ci][kh][kw][cob]);
          float wr[4] = {wv4.x, wv4.y, wv4.z, wv4.w};
#pragma unroll
          for (int cr = 0; cr < 2; cr++) {
            float v0 = strip[cr + kh][kw], v1 = strip[cr + kh][2 + kw];
#pragma unroll
            for (int k = 0; k < 4; k++) {
              acc[cr][0][k] = fmaf(v0, wr[k], acc[cr][0][k]);
              acc[cr][1][k] = fmaf(v1, wr[k], acc[cr][1][k]);
            }
          }
        }
      }
    }
    int pc = colq * 128 + tl;
#pragma unroll
    for (int k = 0; k < 4; k++) {
      float m = fmaxf(fmaxf(acc[0][0][k], acc[0][1][k]),
                      fmaxf(acc[1][0][k], acc[1][1][k]));
      float po = fmaxf(m + bi[cob + k], 0.f);
      h1[(((size_t)n * 16 + cob + k) * 16 + p) * 512 + pc] = po;
      sloc[k] += po;
    }
    __syncthreads();
  }
#pragma unroll
  for (int k = 0; k < 4; k++) {
    float v = sloc[k];
    for (int off = 32; off; off >>= 1) v += __shfl_down(v, off);
    if (l == 0) atomicAdd(&sesum[n * 16 + cob + k], v);
  }
}

// ---------------- SE MLP (generic): mean -> relu fc -> sigmoid fc ----------------
__global__ void k_se(const float* __restrict__ sesum, int C, int Cr, float invcnt,
                     const float* __restrict__ w1, const float* __restrict__ b1,
                     const float* __restrict__ w2, const float* __restrict__ b2,
                     float* __restrict__ s)
{
  int n = blockIdx.x * blockDim.x + threadIdx.x;
  if (n >= 288) return;
  float y[32], t[8];
  for (int c = 0; c < C; c++) y[c] = sesum[n * C + c] * invcnt;
  for (int r = 0; r < Cr; r++) {
    float a = b1[r];
    for (int c = 0; c < C; c++) a += y[c] * w1[r * C + c];
    t[r] = fmaxf(a, 0.f);
  }
  for (int c = 0; c < C; c++) {
    float a = b2[c];
    for (int r = 0; r < Cr; r++) a += t[r] * w2[c * Cr + r];
    s[n * C + c] = 1.f / (1.f + expf(-a));
  }
}

// ---------------- conv2 (SE1 folded) + bn2 + relu + pool + SE2-sum ----------------
// grid: n*8 + ph (full 128-col width); block 512 = cog(4: 8 co each) x tl(128)
// ci double-buffered in chunks of 2; tile rows staged at offset +4 with
// pre-zeroed guard cols [0..3] so strip[0] is a plain scalar LDS read.
__global__ __launch_bounds__(512) void k_conv2(
    const float* __restrict__ h1, const float* __restrict__ w,
    const float* __restrict__ cb, const float* __restrict__ bs,
    const float* __restrict__ bb, const float* __restrict__ bm,
    const float* __restrict__ bv,
    const float* __restrict__ s1,
    float* __restrict__ h2, float* __restrict__ sesum)
{
  int bid = blockIdx.x;
  int ph = bid & 7, n = bid >> 3;
  __shared__ float tile[2][2][4][520];   // [buf][ci][row][4+col], 32.5 KB
  __shared__ float wl[16][3][3][32];     // bn*se1 folded, 18.4 KB
  __shared__ float bi[32];

  const float* s1n = s1 + n * 16;
  for (int i = threadIdx.x; i < 4608; i += 512) {
    int co = i / 144, r = i % 144, ci = r / 9, kk = r % 9;
    float s = bs[co] * rsqrtf(bv[co] + 1e-5f);
    wl[ci][kk / 3][kk % 3][co] = w[i] * s * s1n[ci];
  }
  if (threadIdx.x < 32) {
    int c = threadIdx.x;
    float s = bs[c] * rsqrtf(bv[c] + 1e-5f);
    bi[c] = bb[c] + (cb[c] - bm[c]) * s;
  }
  if (threadIdx.x < 64) {  // zero guard cols [0..3] of all 16 rows (both bufs)
    int b = threadIdx.x >> 5, ci = (threadIdx.x >> 4) & 1,
        r = (threadIdx.x >> 2) & 3, k = threadIdx.x & 3;
    tile[b][ci][r][k] = 0.f;
  }

  const float* hn = h1 + (size_t)n * 16 * 16 * 512;
  int wv = threadIdx.x >> 6, l = threadIdx.x & 63;

  // stage chunk c (ci = 2c, 2c+1) into buf b: 16 wave-loads, 2 per wave
  auto stage = [&](int c, int b) {
#pragma unroll
    for (int j = 0; j < 2; j++) {
      int idx = 2 * wv + j;
      int ci_l = idx >> 3, r = (idx >> 1) & 3, half = idx & 1;
      int ci = 2 * c + ci_l;
      int ih = min(max(2 * ph - 1 + r, 0), 15);
      const float* src = hn + ((size_t)ci * 16 + ih) * 512 + half * 256 + 4 * l;
      GLOAD_LDS(src, &tile[b][ci_l][r][4 + half * 256 + 4 * l]);
    }
  };

  stage(0, 0);
  __syncthreads();

  int cog = threadIdx.x >> 7, tl = threadIdx.x & 127;
  int cob = cog * 8;
  const bool ok0 = (ph > 0), ok3 = (ph < 7);
  float acc[2][2][8];
#pragma unroll
  for (int cr = 0; cr < 2; cr++)
#pragma unroll
    for (int cc = 0; cc < 2; cc++)
#pragma unroll
      for (int k = 0; k < 8; k++) acc[cr][cc][k] = 0.f;

#pragma unroll 1
  for (int c = 0; c < 8; c++) {
    if (c < 7) stage(c + 1, (c + 1) & 1);
    const int b = c & 1;
#pragma unroll 1
    for (int ci_l = 0; ci_l < 2; ci_l++) {
      int cg = 2 * c + ci_l;
      float strip[4][5];
#pragma unroll
      for (int r = 0; r < 4; r++) {
        bool ok = (r == 0) ? ok0 : ((r == 3) ? ok3 : true);
        if (ok) {
          float4 v4 = *reinterpret_cast<const float4*>(&tile[b][ci_l][r][4 * tl + 4]);
          strip[r][0] = tile[b][ci_l][r][4 * tl + 3];
          strip[r][1] = v4.x; strip[r][2] = v4.y; strip[r][3] = v4.z; strip[r][4] = v4.w;
        } else {
          strip[r][0] = strip[r][1] = strip[r][2] = strip[r][3] = strip[r][4] = 0.f;
        }
      }
#pragma unroll
      for (int kh = 0; kh < 3; kh++) {
#pragma unroll
        for (int kw = 0; kw < 3; kw++) {
          const float4* wp = reinterpret_cast<const float4*>(&wl[cg][kh][kw][cob]);
          float4 w0 = wp[0], w1 = wp[1];
          float wr[8] = {w0.x, w0.y, w0.z, w0.w, w1.x, w1.y, w1.z, w1.w};
#pragma unroll
          for (int cr = 0; cr < 2; cr++) {
            float v0 = strip[cr + kh][kw], v1 = strip[cr + kh][2 + kw];
#pragma unroll
            for (int k = 0; k < 8; k++) {
              acc[cr][0][k] = fmaf(v0, wr[k], acc[cr][0][k]);
              acc[cr][1][k] = fmaf(v1, wr[k], acc[cr][1][k]);
            }
          }
        }
      }
    }
    if (c < 7) __syncthreads();
  }

#pragma unroll
  for (int k = 0; k < 8; k++) {
    float m = fmaxf(fmaxf(acc[0][0][k], acc[0][1][k]),
                    fmaxf(acc[1][0][k], acc[1][1][k]));
    float po = fmaxf(m + bi[cob + k], 0.f);
    h2[(((size_t)n * 32 + cob + k) * 8 + ph) * 128 + tl] = po;
    float v = po;
    for (int off = 32; off; off >>= 1) v += __shfl_down(v, off);
    if (l == 0) atomicAdd(&sesum[n * 32 + cob + k], v);
  }
}

// ---------------- conv3 (SE2 folded) + bn3 + relu + global mean ----------------
// grid: n*4 + cog16 (16 co each), block 256 = hh(8) x t(32)
__global__ __launch_bounds__(256) void k_conv3(
    const float* __restrict__ h2, const float* __restrict__ w,
    const float* __restrict__ cb, const float* __restrict__ bs,
    const float* __restrict__ bb, const float* __restrict__ bm,
    const float* __restrict__ bv,
    const float* __restrict__ s2, float* __restrict__ h3)
{
  int bid = blockIdx.x;
  int n = bid >> 2, cog = bid & 3;
  int hh = threadIdx.x >> 5, t = threadIdx.x & 31;
  __shared__ float tile[8][8][128];     // [ci_l][row][col], 32 KB
  __shared__ float wl[32][3][3][16];    // scales folded, 18.4 KB
  __shared__ float bi[16];
  __shared__ float red[4][16];
  __shared__ float zf;
  const float* s2n = s2 + n * 32;
  for (int i = threadIdx.x; i < 4608; i += 256) {
    int k = i / 288, r = i % 288, ci = r / 9, kk = r % 9;
    int co = cog * 16 + k;
    float s = bs[co] * rsqrtf(bv[co] + 1e-5f);
    wl[ci][kk / 3][kk % 3][k] = w[(size_t)co * 288 + r] * s * s2n[ci];
  }
  if (threadIdx.x < 16) {
    int c = cog * 16 + threadIdx.x;
    float s = bs[c] * rsqrtf(bv[c] + 1e-5f);
    bi[threadIdx.x] = bb[c] + (cb[c] - bm[c]) * s;
  }
  if (threadIdx.x == 0) zf = 0.f;
  const float* hn = h2 + (size_t)n * 32 * 8 * 128;
  int wv = threadIdx.x >> 6, l = threadIdx.x & 63;
  float acc[2][16];
#pragma unroll
  for (int cc = 0; cc < 2; cc++)
#pragma unroll
    for (int k = 0; k < 16; k++) acc[cc][k] = 0.f;

#pragma unroll 1
  for (int c = 0; c < 4; c++) {
    // stage 8 ci x 8 rows; one full-wave GLOAD covers 2 rows (256 floats)
    for (int i = 0; i < 8; i++) {
      int pair = wv * 8 + i;
      int ci_l = pair >> 2, r2 = (pair & 3) * 2;
      int ci = c * 8 + ci_l;
      const float* src = hn + ((size_t)ci * 8 + r2) * 128 + 4 * l;
      GLOAD_LDS(src, &tile[ci_l][r2][4 * l]);
    }
    __syncthreads();
#pragma unroll 1
    for (int ci_l = 0; ci_l < 8; ci_l++) {
      int cg = c * 8 + ci_l;
      float strip[3][5];
#pragma unroll
      for (int r = 0; r < 3; r++) {
        int ih = hh - 1 + r;
        if (ih >= 0 && ih <= 7) {
          float4 v4 = *reinterpret_cast<const float4*>(&tile[ci_l][ih][4 * t]);
          const float* ap = t ? &tile[ci_l][ih][4 * t - 1] : &zf;
          strip[r][0] = *ap;
          strip[r][1] = v4.x; strip[r][2] = v4.y; strip[r][3] = v4.z; strip[r][4] = v4.w;
        } else {
          strip[r][0] = strip[r][1] = strip[r][2] = strip[r][3] = strip[r][4] = 0.f;
        }
      }
#pragma unroll
      for (int kh = 0; kh < 3; kh++) {
#pragma unroll
        for (int kw = 0; kw < 3; kw++) {
          const float4* wp = reinterpret_cast<const float4*>(&wl[cg][kh][kw][0]);
          float4 w0 = wp[0], w1 = wp[1], w2 = wp[2], w3 = wp[3];
          float wr[16] = {w0.x, w0.y, w0.z, w0.w, w1.x, w1.y, w1.z, w1.w,
                          w2.x, w2.y, w2.z, w2.w, w3.x, w3.y, w3.z, w3.w};
          float v0 = strip[kh][kw], v1 = strip[kh][2 + kw];
#pragma unroll
          for (int k = 0; k < 16; k++) {
            acc[0][k] = fmaf(v0, wr[k], acc[0][k]);
            acc[1][k] = fmaf(v1, wr[k], acc[1][k]);
          }
        }
      }
    }
    __syncthreads();
  }
#pragma unroll
  for (int k = 0; k < 16; k++)
    acc[0][k] = fmaxf(acc[0][k] + bi[k], 0.f) + fmaxf(acc[1][k] + bi[k], 0.f);
#pragma unroll
  for (int k = 0; k < 16; k++) {
    float v = acc[0][k];
    for (int off = 32; off; off >>= 1) v += __shfl_down(v, off);
    if (l == 0) red[wv][k] = v;
  }
  __syncthreads();
  if (threadIdx.x < 16) {
    int k = threadIdx.x;
    float tt = red[0][k] + red[1][k] + red[2][k] + red[3][k];
    h3[n * 64 + cog * 16 + k] = tt * (1.f / 512.f);
  }
}

// ---------------- head: edge_fc + GNN scatter + e2n + attention + outputs ----------------
__global__ __launch_bounds__(256) void k_head(
    const float* __restrict__ h3,
    const float* __restrict__ efw, const float* __restrict__ efb,
    const float* __restrict__ ew,
    const float* __restrict__ e2nw, const float* __restrict__ e2nb,
    const float* __restrict__ a1w, const float* __restrict__ a1b,
    const float* __restrict__ a2w,
    const float* __restrict__ clsw, const float* __restrict__ clsb,
    const float* __restrict__ regw, const float* __restrict__ regb,
    float* __restrict__ out)
{
  int b = blockIdx.x;
  int tid = threadIdx.x;
  __shared__ float ef[36][64];
  __shared__ float nin[12][64];
  __shared__ float nd[12][128];
  __shared__ float tmp[12][64];
  __shared__ float spw[36], aw[12], scv[12], g[128], ea[36];
  if (tid < 36) {
    float xw = ew[tid];
    spw[tid] = (xw > 20.f) ? xw : log1pf(expf(xw));
  }
  __syncthreads();
  for (int idx = tid; idx < 36 * 64; idx += 256) {
    int e = idx >> 6, d = idx & 63;
    const float* hr = h3 + (size_t)(b * 36 + e) * 64;
    const float* wr = efw + d * 64;
    float a = efb[d];
    for (int k = 0; k < 64; k++) a += hr[k] * wr[k];
    ef[e][d] = fmaxf(a, 0.f) * spw[e];
  }
  __syncthreads();
  for (int idx = tid; idx < 12 * 64; idx += 256) {
    int j = idx >> 6, d = idx & 63;
    float a = 0.f;
    if (j < 6) { for (int i = 0; i < 6; i++) a += ef[j * 6 + i][d]; }
    else       { for (int i = 0; i < 6; i++) a += ef[i * 6 + (j - 6)][d]; }
    nin[j][d] = a;
  }
  __syncthreads();
  for (int idx = tid; idx < 12 * 128; idx += 256) {
    int j = idx >> 7, d = idx & 127;
    const float* wr = e2nw + d * 64;
    float a = e2nb[d];
    for (int k = 0; k < 64; k++) a += nin[j][k] * wr[k];
    nd[j][d] = fmaxf(a, 0.f);
  }
  __syncthreads();
  for (int idx = tid; idx < 12 * 64; idx += 256) {
    int j = idx >> 6, hh = idx & 63;
    const float* wr = a1w + hh * 128;
    float a = a1b[hh];
    for (int k = 0; k < 128; k++) a += nd[j][k] * wr[k];
    tmp[j][hh] = tanhf(a) * a2w[hh];
  }
  __syncthreads();
  if (tid < 12) {
    float a = 0.f;
    for (int h = 0; h < 64; h++) a += tmp[tid][h];
    scv[tid] = a;
  }
  __syncthreads();
  if (tid == 0) {
    float m = scv[0];
    for (int j = 1; j < 12; j++) m = fmaxf(m, scv[j]);
    float s = 0.f;
    for (int j = 0; j < 12; j++) { float z = expf(scv[j] - m); aw[j] = z; s += z; }
    float inv = 1.f / s;
    for (int j = 0; j < 12; j++) aw[j] *= inv;
    float rs = 0.f;
    for (int e = 0; e < 36; e++) { float r = aw[e / 6] * aw[6 + e % 6]; ea[e] = r; rs += r; }
    float inv2 = 1.f / (rs + 1e-8f);
    for (int e = 0; e < 36; e++) ea[e] *= inv2;
  }
  __syncthreads();
  if (tid < 36) out[96 + b * 36 + tid] = ea[tid];
  if (tid < 128) {
    float a = 0.f;
    for (int j = 0; j < 12; j++) a += nd[j][tid] * aw[j];
    g[tid] = a;
  }
  __syncthreads();
  if (tid < 3) {
    const float* wr = regw + tid * 128;
    float a = regb[tid];
    for (int k = 0; k < 128; k++) a += g[k] * wr[k];
    out[b * 3 + tid] = a;
  }
  if (tid >= 64 && tid < 73) {
    int i = tid - 64;
    const float* wr = clsw + i * 128;
    float a = clsb[i];
    for (int k = 0; k < 128; k++) a += g[k] * wr[k];
    out[24 + b * 9 + i] = a;
  }
}

extern "C" void kernel_launch(void* const* d_in, const int* in_sizes, int n_in,
                              void* d_out, int out_size, void* d_ws, size_t ws_size,
                              hipStream_t stream) {
  const float* x      = (const float*)d_in[0];
  const float* c1w    = (const float*)d_in[1];
  const float* c1b    = (const float*)d_in[2];
  const float* bn1s   = (const float*)d_in[3];
  const float* bn1b   = (const float*)d_in[4];
  const float* bn1m   = (const float*)d_in[5];
  const float* bn1v   = (const float*)d_in[6];
  const float* se1w1  = (const float*)d_in[7];
  const float* se1b1  = (const float*)d_in[8];
  const float* se1w2  = (const float*)d_in[9];
  const float* se1b2  = (const float*)d_in[10];
  const float* c2w    = (const float*)d_in[11];
  const float* c2b    = (const float*)d_in[12];
  const float* bn2s   = (const float*)d_in[13];
  const float* bn2b   = (const float*)d_in[14];
  const float* bn2m   = (const float*)d_in[15];
  const float* bn2v   = (const float*)d_in[16];
  const float* se2w1  = (const float*)d_in[17];
  const float* se2b1  = (const float*)d_in[18];
  const float* se2w2  = (const float*)d_in[19];
  const float* se2b2  = (const float*)d_in[20];
  const float* c3w    = (const float*)d_in[21];
  const float* c3b    = (const float*)d_in[22];
  const float* bn3s   = (const float*)d_in[23];
  const float* bn3b   = (const float*)d_in[24];
  const float* bn3m   = (const float*)d_in[25];
  const float* bn3v   = (const float*)d_in[26];
  const float* efw    = (const float*)d_in[27];
  const float* efb    = (const float*)d_in[28];
  const float* ew     = (const float*)d_in[29];
  const float* e2nw   = (const float*)d_in[30];
  const float* e2nb   = (const float*)d_in[31];
  const float* a1w    = (const float*)d_in[32];
  const float* a1b    = (const float*)d_in[33];
  const float* a2w    = (const float*)d_in[34];
  const float* clsw   = (const float*)d_in[35];
  const float* clsb   = (const float*)d_in[36];
  const float* regw   = (const float*)d_in[37];
  const float* regb   = (const float*)d_in[38];

  float* ws = (float*)d_ws;
  float* h1     = ws;                        // 288*16*16*512 = 37,748,736 f
  float* h2     = h1 + 37748736;             // 288*32*8*128  =  9,437,184 f
  float* sesum1 = h2 + 9437184;              // 4608 f
  float* s1     = sesum1 + 4608;             // 4608 f
  float* sesum2 = s1 + 4608;                 // 9216 f
  float* s2     = sesum2 + 9216;             // 9216 f
  float* h3     = s2 + 9216;                 // 18432 f

  hipMemsetAsync(sesum1, 0, 4608 * sizeof(float), stream);
  hipMemsetAsync(sesum2, 0, 9216 * sizeof(float), stream);

  k_conv1<<<288 * 16, 512, 0, stream>>>(x, c1w, c1b, bn1s, bn1b, bn1m, bn1v, h1, sesum1);
  k_se<<<5, 64, 0, stream>>>(sesum1, 16, 4, 1.f / 8192.f, se1w1, se1b1, se1w2, se1b2, s1);
  k_conv2<<<288 * 8, 512, 0, stream>>>(h1, c2w, c2b, bn2s, bn2b, bn2m, bn2v, s1, h2, sesum2);
  k_se<<<5, 64, 0, stream>>>(sesum2, 32, 8, 1.f / 1024.f, se2w1, se2b1, se2w2, se2b2, s2);
  k_conv3<<<288 * 4, 256, 0, stream>>>(h2, c3w, c3b, bn3s, bn3b, bn3m, bn3v, s2, h3);
  k_head<<<8, 256, 0, stream>>>(h3, efw, efb, ew, e2nw, e2nb, a1w, a1b, a2w,
                                clsw, clsb, regw, regb, (float*)d_out);
}